// Round 7
// baseline (340.657 us; speedup 1.0000x reference)
//
#include <hip/hip_runtime.h>
#include <cstdint>
#include <cstddef>

// ---------------- problem constants ----------------
#define NN 50000
#define EE 1600000
#define IN_DIM 256
#define HC 128      // HEADS*C
#define CD 32       // C
#define BN_RS 0.9999950000374997f  // 1/sqrt(1+1e-5)

#define CAP1 96     // deg ~ Poisson(32): P(deg>96) ~ 0 -> spill path is cold
#define CAP2 128
#define NBKT 196    // ceil(NN/256) buckets of 256 dst nodes
#define BCAP 10240  // padded per-bucket capacity (mean 8163, sd ~90 -> 23 sigma slack)
#define S1_B 782    // stage1 blocks: (EE+2047)/2048
#define G1_B 782    // gemm1 blocks (4 waves x 16 rows)

typedef __attribute__((ext_vector_type(8))) short short8;   // 8 bf16 (bit pattern)
typedef __attribute__((ext_vector_type(4))) float f32x4;

// ---------------- small helpers ----------------
__device__ __forceinline__ float lrelu(float a) { return a > 0.f ? a : 0.2f * a; }
__device__ __forceinline__ float elu(float a) { return a > 0.f ? a : (__expf(a) - 1.f); }

__device__ __forceinline__ unsigned short f2bf(float f) {
    unsigned int u = __float_as_uint(f);
    unsigned int r = (u + 0x7FFFu + ((u >> 16) & 1u)) >> 16;
    return (unsigned short)r;
}
__device__ __forceinline__ float bf2f(unsigned short b) {
    return __uint_as_float(((unsigned int)b) << 16);
}
__device__ __forceinline__ float2 bf2f2(unsigned int p) {
    float2 r;
    r.x = __uint_as_float(p << 16);
    r.y = __uint_as_float(p & 0xFFFF0000u);
    return r;
}
__device__ __forceinline__ void unpack_edge(unsigned long long p, int& s, float& eav) {
    s = (int)(unsigned int)(p & 0xFFFFFFFFull);
    eav = __uint_as_float((unsigned int)(p >> 32));
}
// select one of 4 by runtime index without scratch-spilling arrays (rule #20)
__device__ __forceinline__ float pick4(float a, float b, float c, float d, int h) {
    return (h & 2) ? ((h & 1) ? d : c) : ((h & 1) ? b : a);
}

// 256-thread exclusive scan (ONE internal barrier; all 256 must call)
__device__ __forceinline__ int block_excl_scan_256(int v, int tid, int* wsum) {
    int lane = tid & 63, wv = tid >> 6;
    int x = v;
    #pragma unroll
    for (int off = 1; off < 64; off <<= 1) {
        int y = __shfl_up(x, off);
        if (lane >= off) x += y;
    }
    if (lane == 63) wsum[wv] = x;
    __syncthreads();
    int wpre = 0;
    #pragma unroll
    for (int w = 0; w < 4; w++)
        if (w < wv) wpre += wsum[w];
    return wpre + x - v;
}

// ---------------- K0: W1/W2 frag prepack + attn consts + cursor zero-init ----------
__global__ __launch_bounds__(256) void k0_prep(const float* __restrict__ W1,
                                               const float* __restrict__ W2,
                                               const float* __restrict__ We1,
                                               const float* __restrict__ ae1,
                                               const float* __restrict__ We2,
                                               const float* __restrict__ ae2,
                                               unsigned short* __restrict__ W1hi,
                                               unsigned short* __restrict__ W1lo,
                                               unsigned short* __restrict__ W2hi,
                                               unsigned short* __restrict__ W2lo,
                                               float* __restrict__ consts,
                                               int* __restrict__ bucketCursor) {
    int blk = blockIdx.x;
    int tid = threadIdx.x;
    if (blk < 16) {
        // W1 [256,128] -> frag order ((nt*8+kt)*64+lane)*8+j, split hi/lo
        int t = blk * 256 + tid;
        int lane = t & 63;
        int kt = (t >> 6) & 7;
        int nt = t >> 9;
        int kbase = kt * 32 + (lane >> 4) * 8;
        int col = nt * 16 + (lane & 15);
        size_t obase = (size_t)t * 8;
        #pragma unroll
        for (int j = 0; j < 8; j++) {
            float w = W1[(size_t)(kbase + j) * HC + col];
            unsigned short h = f2bf(w);
            W1hi[obase + j] = h;
            W1lo[obase + j] = f2bf(w - bf2f(h));
        }
    } else if (blk < 18) {
        // W2 [128,32] -> frag order ((nt*4+kt)*64+lane)*8+j, split hi/lo
        int t = (blk - 16) * 256 + tid;  // 0..511
        int lane = t & 63;
        int kt = (t >> 6) & 3;
        int nt = t >> 8;
        int kbase = kt * 32 + (lane >> 4) * 8;
        int col = nt * 16 + (lane & 15);
        size_t obase = (size_t)t * 8;
        #pragma unroll
        for (int j = 0; j < 8; j++) {
            float w = W2[(size_t)(kbase + j) * CD + col];
            unsigned short h = f2bf(w);
            W2hi[obase + j] = h;
            W2lo[obase + j] = f2bf(w - bf2f(h));
        }
    } else {
        if (tid < NBKT) bucketCursor[tid] = 0;
        if (tid == 200) consts[0] = 0.f;     // easum accumulator
        if (tid < 4) {
            float s = 0.f;
            for (int c = 0; c < 32; c++) s += We1[tid * 32 + c] * ae1[tid * 32 + c];
            consts[2 + tid] = s;
        } else if (tid == 4) {
            float s = 0.f;
            for (int c = 0; c < 32; c++) s += We2[c] * ae2[c];
            consts[6] = s;
        }
    }
}

// ---------------- gemm1 (MFMA split-bf16) + fused al1 — ZERO LDS, high occupancy ----
// al1 epilogue computes als1/ald1 straight from the MFMA accumulators (no re-read).
__global__ __launch_bounds__(256) void gemm1_al1(const float* __restrict__ x,
                                                 const unsigned short* __restrict__ W1hi,
                                                 const unsigned short* __restrict__ W1lo,
                                                 const float* __restrict__ as1,
                                                 const float* __restrict__ ad1,
                                                 float* __restrict__ als,
                                                 float* __restrict__ ald,
                                                 unsigned short* __restrict__ xs1b) {
    int tid = threadIdx.x;
    int lane = tid & 63, wv = tid >> 6;
    int row0 = blockIdx.x * 64 + wv * 16;
    if (row0 >= NN) return;
    int m = lane & 15;
    int q = lane >> 4;
    f32x4 acc[8];
    #pragma unroll
    for (int nt = 0; nt < 8; nt++) acc[nt] = {0.f, 0.f, 0.f, 0.f};
    const float* xrow = x + (size_t)(row0 + m) * IN_DIM + q * 8;
    #pragma unroll
    for (int kt = 0; kt < 8; kt++) {
        float4 v0 = *(const float4*)(xrow + kt * 32);
        float4 v1 = *(const float4*)(xrow + kt * 32 + 4);
        float vv[8] = {v0.x, v0.y, v0.z, v0.w, v1.x, v1.y, v1.z, v1.w};
        short8 ahi, alo;
        #pragma unroll
        for (int j = 0; j < 8; j++) {
            unsigned short hh = f2bf(vv[j]);
            ahi[j] = (short)hh;
            alo[j] = (short)f2bf(vv[j] - bf2f(hh));
        }
        #pragma unroll
        for (int nt = 0; nt < 8; nt++) {
            size_t fb = ((size_t)(nt * 8 + kt) * 64 + lane) * 8;
            short8 bhi = *(const short8*)(W1hi + fb);
            short8 blo = *(const short8*)(W1lo + fb);
            acc[nt] = __builtin_amdgcn_mfma_f32_16x16x32_bf16(ahi, bhi, acc[nt], 0, 0, 0);
            acc[nt] = __builtin_amdgcn_mfma_f32_16x16x32_bf16(ahi, blo, acc[nt], 0, 0, 0);
            acc[nt] = __builtin_amdgcn_mfma_f32_16x16x32_bf16(alo, bhi, acc[nt], 0, 0, 0);
        }
    }
    #pragma unroll
    for (int nt = 0; nt < 8; nt++) {
        #pragma unroll
        for (int rg = 0; rg < 4; rg++) {
            int row = row0 + q * 4 + rg;
            xs1b[(size_t)row * HC + nt * 16 + m] = f2bf(acc[nt][rg]);
        }
    }
    // ---- fused al1: als/ald from accumulators (col nt*16+m; head h = cols h*32..+31)
    float a_s0[4], a_s1[4], a_d0[4], a_d1[4];
    #pragma unroll
    for (int h = 0; h < 4; h++) {
        a_s0[h] = as1[h * 32 + m];
        a_s1[h] = as1[h * 32 + 16 + m];
        a_d0[h] = ad1[h * 32 + m];
        a_d1[h] = ad1[h * 32 + 16 + m];
    }
    #pragma unroll
    for (int rg = 0; rg < 4; rg++) {
        int row = row0 + q * 4 + rg;
        #pragma unroll
        for (int h = 0; h < 4; h++) {
            float s = acc[2 * h][rg] * a_s0[h] + acc[2 * h + 1][rg] * a_s1[h];
            float d = acc[2 * h][rg] * a_d0[h] + acc[2 * h + 1][rg] * a_d1[h];
            #pragma unroll
            for (int off = 1; off < 16; off <<= 1) {
                s += __shfl_xor(s, off);
                d += __shfl_xor(d, off);
            }
            if (m == 0) {
                als[(size_t)row * 4 + h] = s;
                ald[(size_t)row * 4 + h] = d;
            }
        }
    }
}

// ---------------- stage1: padded-bucket bin + easum (LDS-heavy, homogeneous) -------
// record: w0 = src | (dst&255)<<24 (bucket implicit in padded position), w1 = ea
__global__ __launch_bounds__(256) void stage1_kernel(const int* __restrict__ ei,
                                                     const float* __restrict__ ea,
                                                     int* __restrict__ bucketCursor,
                                                     uint2* __restrict__ Apack,
                                                     float* __restrict__ consts) {
    __shared__ int cnt[256];
    __shared__ int basel[256];
    __shared__ int gbase[256];
    __shared__ int wsum[4];
    __shared__ int sdst[2048];
    __shared__ int ssrc[2048];
    __shared__ float sea[2048];
    int tid = threadIdx.x;
    int base = blockIdx.x * 2048;
    cnt[tid] = 0;
    __syncthreads();
    int d[8], s[8], r[8], bk[8];
    float e[8];
    float se = 0.f;
    #pragma unroll
    for (int k = 0; k < 8; k++) {
        int i = base + k * 256 + tid;
        if (i < EE) {
            d[k] = ei[EE + i];
            s[k] = ei[i];
            e[k] = ea[i];
            se += e[k];
            bk[k] = d[k] >> 8;
            r[k] = atomicAdd(&cnt[bk[k]], 1);   // LDS returning atomic: cheap
        } else d[k] = -1;
    }
    // easum partial (was in the removed hist pass)
    #pragma unroll
    for (int off = 32; off > 0; off >>= 1) se += __shfl_xor(se, off);
    if ((tid & 63) == 0) atomicAdd(&consts[0], se);
    __syncthreads();
    int v = cnt[tid];
    int excl = block_excl_scan_256(v, tid, wsum);
    basel[tid] = excl;
    if (tid < NBKT && v > 0) gbase[tid] = atomicAdd(&bucketCursor[tid], v);
    __syncthreads();
    #pragma unroll
    for (int k = 0; k < 8; k++) {
        if (d[k] >= 0) {
            int slot = basel[bk[k]] + r[k];
            sdst[slot] = d[k];
            ssrc[slot] = s[k];
            sea[slot] = e[k];
        }
    }
    __syncthreads();
    int total = basel[255] + cnt[255];
    for (int slot = tid; slot < total; slot += 256) {
        int dd = sdst[slot];
        int b = dd >> 8;
        int off = gbase[b] + (slot - basel[b]);
        if (off < BCAP)   // safety guard; never taken for this input
            Apack[(size_t)b * BCAP + off] =
                make_uint2((unsigned int)ssrc[slot] | ((unsigned int)(dd & 255) << 24),
                           __float_as_uint(sea[slot]));
    }
}

// ---------------- stage2 (1024 threads): per-bucket counting sort -> indptr/degv/edgedat
__global__ __launch_bounds__(1024) void stage2_kernel(const int* __restrict__ bucketCursor,
                                                      const uint2* __restrict__ Apack,
                                                      int* __restrict__ indptr,
                                                      unsigned short* __restrict__ degv,
                                                      unsigned long long* __restrict__ edgedat,
                                                      float* __restrict__ consts) {
    __shared__ int cnt[256];
    __shared__ int dbase[257];
    int tid = threadIdx.x;
    int b = blockIdx.x;
    int count = bucketCursor[b];
    if (count > BCAP) count = BCAP;
    size_t start = (size_t)b * BCAP;
    if (b == 0 && tid == 0) consts[1] = consts[0] / (float)EE;  // ea_mean (easum final)
    if (tid < 256) cnt[tid] = 0;
    __syncthreads();
    for (int i = tid; i < count; i += 1024) atomicAdd(&cnt[Apack[start + i].x >> 24], 1);
    __syncthreads();
    // exclusive scan of 256 bins by wave 0 (4 bins/lane); dbase[256] = total
    if (tid < 64) {
        int b4 = tid * 4;
        int c0 = cnt[b4], c1 = cnt[b4 + 1], c2 = cnt[b4 + 2], c3 = cnt[b4 + 3];
        int t = c0 + c1 + c2 + c3;
        int x = t;
        #pragma unroll
        for (int off = 1; off < 64; off <<= 1) {
            int y = __shfl_up(x, off);
            if (tid >= off) x += y;
        }
        int e0 = x - t;
        dbase[b4] = e0;
        dbase[b4 + 1] = e0 + c0;
        dbase[b4 + 2] = e0 + c0 + c1;
        dbase[b4 + 3] = e0 + c0 + c1 + c2;
        if (tid == 63) dbase[256] = x;
    }
    __syncthreads();
    if (tid < 256) {
        int n = b * 256 + tid;
        if (n < NN) {
            indptr[n] = (int)start + dbase[tid];
            degv[n] = (unsigned short)(dbase[tid + 1] - dbase[tid]);
        }
        cnt[tid] = 0;          // reuse as per-dst cursor
    }
    __syncthreads();
    for (int i = tid; i < count; i += 1024) {
        uint2 p = Apack[start + i];
        int dl = p.x >> 24;
        int r = atomicAdd(&cnt[dl], 1);
        edgedat[start + dbase[dl] + r] = (unsigned long long)(p.x & 0xFFFFFFu) |
                                         ((unsigned long long)p.y << 32);
    }
}

// accumulate one gathered uint2 (4 bf16 cols) with raw weight ww
#define ACC4(vv, ww) { float2 p0_ = bf2f2((vv).x); float2 p1_ = bf2f2((vv).y); \
    acc0 += p0_.x * (ww); acc1 += p0_.y * (ww); acc2 += p1_.x * (ww); acc3 += p1_.y * (ww); }

// ---------------- conv1 aggregation + FUSED gemm2 (h1 never leaves the block) ------
#define H1P 136   // h1 LDS row pitch (ushorts): 272B = 16B-aligned, spreads banks
__global__ __launch_bounds__(256, 8) void gat1_gemm2(
    const unsigned short* __restrict__ xs1b, const float* __restrict__ als,
    const float* __restrict__ ald, const unsigned long long* __restrict__ edgedat,
    const int* __restrict__ indptr, const unsigned short* __restrict__ degv,
    const float* __restrict__ consts,
    const float* __restrict__ b1, const float* __restrict__ g1,
    const float* __restrict__ be1,
    const unsigned short* __restrict__ W2hi, const unsigned short* __restrict__ W2lo,
    const float* __restrict__ as2, const float* __restrict__ ad2,
    unsigned short* __restrict__ xs2b, float* __restrict__ als2,
    float* __restrict__ ald2) {
    __shared__ __align__(16) float exbuf[8][CAP1][4];
    __shared__ int srcbuf[8][CAP1];
    __shared__ __align__(16) unsigned short h1hi_s[8][H1P];
    __shared__ __align__(16) unsigned short h1lo_s[8][H1P];
    int tid = threadIdx.x;
    int l = tid & 31;            // lane within half-wave
    int nb = tid >> 5;           // node slot 0..7
    int n = blockIdx.x * 8 + nb;
    int start = indptr[n];
    int deg = degv[n];
    float ea_mean = consts[1];
    float ce0 = consts[2], ce1 = consts[3], ce2 = consts[4], ce3 = consts[5];
    float4 a4d = *(const float4*)(ald + (size_t)n * 4);
    float4 a4s = *(const float4*)(als + (size_t)n * 4);
    float ex00 = __expf(lrelu(a4s.x + a4d.x + ea_mean * ce0));
    float ex01 = __expf(lrelu(a4s.y + a4d.y + ea_mean * ce1));
    float ex02 = __expf(lrelu(a4s.z + a4d.z + ea_mean * ce2));
    float ex03 = __expf(lrelu(a4s.w + a4d.w + ea_mean * ce3));
    float sm0 = 0.f, sm1 = 0.f, sm2 = 0.f, sm3 = 0.f;
    const unsigned long long* edp = edgedat + start;
    // phase 1: raw exp weights -> LDS, per-head partial sums
    for (int i = l; i < deg; i += 32) {
        int s; float eav;
        unpack_edge(edp[i], s, eav);
        float4 v4 = *(const float4*)(als + (size_t)s * 4);
        float4 ex4;
        ex4.x = __expf(lrelu(v4.x + a4d.x + eav * ce0)); sm0 += ex4.x;
        ex4.y = __expf(lrelu(v4.y + a4d.y + eav * ce1)); sm1 += ex4.y;
        ex4.z = __expf(lrelu(v4.z + a4d.z + eav * ce2)); sm2 += ex4.z;
        ex4.w = __expf(lrelu(v4.w + a4d.w + eav * ce3)); sm3 += ex4.w;
        if (i < CAP1) {
            srcbuf[nb][i] = s * (HC * 2);                   // byte offset of src row
            *(float4*)(&exbuf[nb][i][0]) = ex4;
        }
    }
    #pragma unroll
    for (int off = 16; off > 0; off >>= 1) {
        sm0 += __shfl_xor(sm0, off);
        sm1 += __shfl_xor(sm1, off);
        sm2 += __shfl_xor(sm2, off);
        sm3 += __shfl_xor(sm3, off);
    }
    int h2 = l >> 3;                                         // this lane's head
    float ex0sel = pick4(ex00, ex01, ex02, ex03, h2);
    float inv = 1.0f / (pick4(sm0, sm1, sm2, sm3, h2) + ex0sel + 1e-16f);
    int mcap = deg < CAP1 ? deg : CAP1;
    const char* xb = (const char*)xs1b + (size_t)l * 8;      // lane's 4 cols (8B)
    float acc0, acc1, acc2, acc3;
    {   // self loop (raw weight)
        uint2 v = *(const uint2*)(xb + (size_t)n * (HC * 2));
        float2 p0 = bf2f2(v.x), p1 = bf2f2(v.y);
        acc0 = p0.x * ex0sel; acc1 = p0.y * ex0sel;
        acc2 = p1.x * ex0sel; acc3 = p1.y * ex0sel;
    }
    // phase 2: weighted gather, 8 loads in flight
    int i = 0;
    for (; i + 8 <= mcap; i += 8) {
        int o0 = srcbuf[nb][i + 0], o1 = srcbuf[nb][i + 1];
        int o2 = srcbuf[nb][i + 2], o3 = srcbuf[nb][i + 3];
        int o4 = srcbuf[nb][i + 4], o5 = srcbuf[nb][i + 5];
        int o6 = srcbuf[nb][i + 6], o7 = srcbuf[nb][i + 7];
        float w0 = exbuf[nb][i + 0][h2], w1 = exbuf[nb][i + 1][h2];
        float w2 = exbuf[nb][i + 2][h2], w3 = exbuf[nb][i + 3][h2];
        float w4 = exbuf[nb][i + 4][h2], w5 = exbuf[nb][i + 5][h2];
        float w6 = exbuf[nb][i + 6][h2], w7 = exbuf[nb][i + 7][h2];
        uint2 v0 = *(const uint2*)(xb + o0);
        uint2 v1 = *(const uint2*)(xb + o1);
        uint2 v2 = *(const uint2*)(xb + o2);
        uint2 v3 = *(const uint2*)(xb + o3);
        uint2 v4 = *(const uint2*)(xb + o4);
        uint2 v5 = *(const uint2*)(xb + o5);
        uint2 v6 = *(const uint2*)(xb + o6);
        uint2 v7 = *(const uint2*)(xb + o7);
        ACC4(v0, w0); ACC4(v1, w1); ACC4(v2, w2); ACC4(v3, w3);
        ACC4(v4, w4); ACC4(v5, w5); ACC4(v6, w6); ACC4(v7, w7);
    }
    for (; i < mcap; i++) {
        int o = srcbuf[nb][i];
        float w = exbuf[nb][i][h2];
        uint2 v = *(const uint2*)(xb + o);
        ACC4(v, w);
    }
    if (deg > CAP1) {   // spill fallback (deg > CAP1): recompute raw weights (cold)
        float aldsel = pick4(a4d.x, a4d.y, a4d.z, a4d.w, h2);
        float cesel = pick4(ce0, ce1, ce2, ce3, h2);
        for (int j = CAP1; j < deg; j++) {
            int s; float eav;
            unpack_edge(edp[j], s, eav);
            float w = __expf(lrelu(als[(size_t)s * 4 + h2] + aldsel + eav * cesel));
            uint2 v = *(const uint2*)(xb + (size_t)s * (HC * 2));
            ACC4(v, w);
        }
    }
    acc0 *= inv; acc1 *= inv; acc2 *= inv; acc3 *= inv;
    int c = l * 4;
    float4 bb = *(const float4*)(b1 + c);
    float4 gg = *(const float4*)(g1 + c);
    float4 eb = *(const float4*)(be1 + c);
    float o0 = elu((acc0 + bb.x) * (gg.x * BN_RS) + eb.x);
    float o1 = elu((acc1 + bb.y) * (gg.y * BN_RS) + eb.y);
    float o2 = elu((acc2 + bb.z) * (gg.z * BN_RS) + eb.z);
    float o3 = elu((acc3 + bb.w) * (gg.w * BN_RS) + eb.w);
    // split hi/lo bf16 into LDS for the fused gemm2
    unsigned short h0 = f2bf(o0), h1v = f2bf(o1), h2v = f2bf(o2), h3v = f2bf(o3);
    unsigned short l0 = f2bf(o0 - bf2f(h0)), l1 = f2bf(o1 - bf2f(h1v));
    unsigned short l2 = f2bf(o2 - bf2f(h2v)), l3 = f2bf(o3 - bf2f(h3v));
    uint2 hiw, low;
    hiw.x = (unsigned int)h0 | ((unsigned int)h1v << 16);
    hiw.y = (unsigned int)h2v | ((unsigned int)h3v << 16);
    low.x = (unsigned int)l0 | ((unsigned int)l1 << 16);
    low.y = (unsigned int)l2 | ((unsigned int)l3 << 16);
    *(uint2*)(&h1hi_s[nb][c]) = hiw;
    *(uint2*)(&h1lo_s[nb][c]) = low;
    __syncthreads();             // h1 tile complete
    if (tid >= 64) return;       // waves 1-3 done

    // ---- wave 0: gemm2 (16x16x32 MFMA) for rows n0..n0+7 ----
    int lane = tid;              // 0..63
    int m = lane & 15, q = lane >> 4;
    int r8 = m & 7;              // rows 8..15 duplicate 0..7 (outputs discarded)
    f32x4 g2acc0 = {0.f, 0.f, 0.f, 0.f};
    f32x4 g2acc1 = {0.f, 0.f, 0.f, 0.f};
    #pragma unroll
    for (int kt = 0; kt < 4; kt++) {
        short8 ahi = *(const short8*)(&h1hi_s[r8][q * 8 + kt * 32]);
        short8 alo = *(const short8*)(&h1lo_s[r8][q * 8 + kt * 32]);
        size_t fb0 = ((size_t)kt * 64 + lane) * 8;
        size_t fb1 = ((size_t)(4 + kt) * 64 + lane) * 8;
        short8 bhi0 = *(const short8*)(W2hi + fb0);
        short8 blo0 = *(const short8*)(W2lo + fb0);
        short8 bhi1 = *(const short8*)(W2hi + fb1);
        short8 blo1 = *(const short8*)(W2lo + fb1);
        g2acc0 = __builtin_amdgcn_mfma_f32_16x16x32_bf16(ahi, bhi0, g2acc0, 0, 0, 0);
        g2acc0 = __builtin_amdgcn_mfma_f32_16x16x32_bf16(ahi, blo0, g2acc0, 0, 0, 0);
        g2acc0 = __builtin_amdgcn_mfma_f32_16x16x32_bf16(alo, bhi0, g2acc0, 0, 0, 0);
        g2acc1 = __builtin_amdgcn_mfma_f32_16x16x32_bf16(ahi, bhi1, g2acc1, 0, 0, 0);
        g2acc1 = __builtin_amdgcn_mfma_f32_16x16x32_bf16(ahi, blo1, g2acc1, 0, 0, 0);
        g2acc1 = __builtin_amdgcn_mfma_f32_16x16x32_bf16(alo, bhi1, g2acc1, 0, 0, 0);
    }
    int n0 = blockIdx.x * 8;
    float a0 = as2[m], a1 = as2[m + 16];
    float d0 = ad2[m], d1 = ad2[m + 16];
    #pragma unroll
    for (int rg = 0; rg < 4; rg++) {
        int rloc = q * 4 + rg;       // 0..15; valid output rows are 0..7
        float s = g2acc0[rg] * a0 + g2acc1[rg] * a1;
        float d = g2acc0[rg] * d0 + g2acc1[rg] * d1;
        #pragma unroll
        for (int off = 1; off < 16; off <<= 1) {
            s += __shfl_xor(s, off);
            d += __shfl_xor(d, off);
        }
        if (rloc < 8) {
            int row = n0 + rloc;
            xs2b[(size_t)row * CD + m]      = f2bf(g2acc0[rg]);
            xs2b[(size_t)row * CD + 16 + m] = f2bf(g2acc1[rg]);
            if (m == 0) { als2[row] = s; ald2[row] = d; }
        }
    }
}

// ---------------- conv2 aggregation + fused MLP heads (raw-acc + post-scale) --------
__global__ __launch_bounds__(256) void gat2_agg(
    const unsigned short* __restrict__ xs2b, const float* __restrict__ als,
    const float* __restrict__ ald, const unsigned long long* __restrict__ edgedat,
    const int* __restrict__ indptr, const unsigned short* __restrict__ degv,
    const float* __restrict__ consts,
    const float* __restrict__ b2, const float* __restrict__ g2, const float* __restrict__ be2,
    const float* __restrict__ Wc1, const float* __restrict__ bc1,
    const float* __restrict__ Wc2, const float* __restrict__ bc2,
    const float* __restrict__ Wr1, const float* __restrict__ br1,
    const float* __restrict__ Wr2, const float* __restrict__ br2,
    float* __restrict__ hout, float* __restrict__ cls, float* __restrict__ reg) {
    __shared__ float exbuf[4][CAP2];
    __shared__ int srcbuf[4][CAP2];
    __shared__ __align__(16) float hbuf[4][32];
    int wv = threadIdx.x >> 6;
    int lane = threadIdx.x & 63;
    int n = blockIdx.x * 4 + wv;
    int start = indptr[n];
    int deg = degv[n];
    float ea_mean = consts[1];
    float ce = consts[6];
    float aldn = ald[n];
    float ex0 = __expf(lrelu(als[n] + aldn + ea_mean * ce));
    float sm = 0.f;
    const unsigned long long* edp = edgedat + start;
    for (int i = lane; i < deg; i += 64) {
        int s; float eav;
        unpack_edge(edp[i], s, eav);
        float exv = __expf(lrelu(als[s] + aldn + eav * ce));
        if (i < CAP2) { srcbuf[wv][i] = s * (CD * 2); exbuf[wv][i] = exv; }
        sm += exv;
    }
    #pragma unroll
    for (int off = 32; off > 0; off >>= 1) sm += __shfl_xor(sm, off);
    float invd = 1.0f / (sm + ex0 + 1e-16f);
    int mcap = deg < CAP2 ? deg : CAP2;
    int oct = lane >> 3, lo = lane & 7;
    const char* xb = (const char*)xs2b + (size_t)lo * 8;     // lane's 4 cols (8B)
    float acc0 = 0.f, acc1 = 0.f, acc2 = 0.f, acc3 = 0.f;
    if (oct == 0) {   // self loop (raw weight), counted once after oct-reduce
        uint2 v = *(const uint2*)(xb + (size_t)n * (CD * 2));
        float2 p0 = bf2f2(v.x), p1 = bf2f2(v.y);
        acc0 = p0.x * ex0; acc1 = p0.y * ex0; acc2 = p1.x * ex0; acc3 = p1.y * ex0;
    }
    for (int i = oct; i < mcap; i += 8) {
        float w = exbuf[wv][i];
        int o = srcbuf[wv][i];
        uint2 v = *(const uint2*)(xb + o);
        ACC4(v, w);
    }
    for (int i = CAP2 + oct; i < deg; i += 8) {  // spill fallback (raw weights)
        int s; float eav;
        unpack_edge(edp[i], s, eav);
        float w = __expf(lrelu(als[s] + aldn + eav * ce));
        uint2 v = *(const uint2*)(xb + (size_t)s * (CD * 2));
        ACC4(v, w);
    }
    #pragma unroll
    for (int off = 8; off < 64; off <<= 1) {
        acc0 += __shfl_xor(acc0, off);
        acc1 += __shfl_xor(acc1, off);
        acc2 += __shfl_xor(acc2, off);
        acc3 += __shfl_xor(acc3, off);
    }
    if (lane < 8) {
        int c = lo * 4;
        float4 bb = *(const float4*)(b2 + c);
        float4 gg = *(const float4*)(g2 + c);
        float4 eb = *(const float4*)(be2 + c);
        float o0 = elu((acc0 * invd + bb.x) * (gg.x * BN_RS) + eb.x);
        float o1 = elu((acc1 * invd + bb.y) * (gg.y * BN_RS) + eb.y);
        float o2 = elu((acc2 * invd + bb.z) * (gg.z * BN_RS) + eb.z);
        float o3 = elu((acc3 * invd + bb.w) * (gg.w * BN_RS) + eb.w);
        *(float4*)(&hbuf[wv][c]) = make_float4(o0, o1, o2, o3);
        *(float4*)(hout + (size_t)n * CD + c) = make_float4(o0, o1, o2, o3);
    }
    // intra-wave LDS RAW: no block barrier needed (hbuf is per-wave)
    float r0 = 0.f, r1 = 0.f;
    if (lane < 32) {
        int j = lane & 15;
        bool iscls = lane < 16;
        float s = iscls ? bc1[j] : br1[j];
        #pragma unroll
        for (int cc = 0; cc < 32; cc++) {
            float w = iscls ? Wc1[cc * 16 + j] : Wr1[cc * 16 + j];
            s += hbuf[wv][cc] * w;
        }
        s = fmaxf(s, 0.f);
        if (iscls) { r0 = s * Wc2[j * 2]; r1 = s * Wc2[j * 2 + 1]; }
        else       { r0 = s * Wr2[j]; }
    }
    #pragma unroll
    for (int off = 1; off < 16; off <<= 1) {
        r0 += __shfl_xor(r0, off);
        r1 += __shfl_xor(r1, off);
    }
    if (lane == 0)  *(float2*)(cls + (size_t)n * 2) = make_float2(r0 + bc2[0], r1 + bc2[1]);
    if (lane == 16) reg[n] = r0 + br2[0];
}

// ---------------- launch ----------------
extern "C" void kernel_launch(void* const* d_in, const int* in_sizes, int n_in,
                              void* d_out, int out_size, void* d_ws, size_t ws_size,
                              hipStream_t stream) {
    const float* x   = (const float*)d_in[0];
    const int*   ei  = (const int*)d_in[1];
    const float* ea  = (const float*)d_in[2];
    const float* W1  = (const float*)d_in[3];
    const float* as1 = (const float*)d_in[4];
    const float* ad1 = (const float*)d_in[5];
    const float* We1 = (const float*)d_in[6];
    const float* ae1 = (const float*)d_in[7];
    const float* b1  = (const float*)d_in[8];
    const float* g1  = (const float*)d_in[9];
    const float* be1 = (const float*)d_in[10];
    const float* W2  = (const float*)d_in[11];
    const float* as2 = (const float*)d_in[12];
    const float* ad2 = (const float*)d_in[13];
    const float* We2 = (const float*)d_in[14];
    const float* ae2 = (const float*)d_in[15];
    const float* b2  = (const float*)d_in[16];
    const float* g2  = (const float*)d_in[17];
    const float* be2 = (const float*)d_in[18];
    const float* Wc1 = (const float*)d_in[19];
    const float* bc1 = (const float*)d_in[20];
    const float* Wc2 = (const float*)d_in[21];
    const float* bc2 = (const float*)d_in[22];
    const float* Wr1 = (const float*)d_in[23];
    const float* br1 = (const float*)d_in[24];
    const float* Wr2 = (const float*)d_in[25];
    const float* br2 = (const float*)d_in[26];

    char* ws = (char*)d_ws;
    unsigned short* xs1b = (unsigned short*)(ws + 0);          // N*128 bf16 = 12.8 MB
    uint2* Apack         = (uint2*)(ws + 12800000);            // 196*BCAP*8 = 16.06 MB
    unsigned long long* edgedat = (unsigned long long*)(ws + 28856320);  // 16.06 MB
    unsigned short* xs2b = (unsigned short*)(ws + 44912640);   // N*32 bf16 = 3.2 MB
    float* als1          = (float*)(ws + 48112640);            // N*4 f32
    float* ald1          = (float*)(ws + 48912640);            // N*4 f32
    float* als2          = (float*)(ws + 49712640);            // N f32
    float* ald2          = (float*)(ws + 49912640);            // N f32
    float* consts        = (float*)(ws + 50112640);            // 16 floats
    int*   bucketCursor  = (int*)(ws + 50112704);              // 196
    int*   indptr        = (int*)(ws + 50113488);              // NN
    unsigned short* degv = (unsigned short*)(ws + 50313488);   // NN u16
    unsigned short* W1hi = (unsigned short*)(ws + 50413488);   // 64 KB
    unsigned short* W1lo = (unsigned short*)(ws + 50479024);   // 64 KB
    unsigned short* W2hi = (unsigned short*)(ws + 50544560);   // 8 KB
    unsigned short* W2lo = (unsigned short*)(ws + 50552752);   // 8 KB (ends ~50.56 MB)

    float* out_cls = (float*)d_out;            // [N,2]
    float* out_reg = out_cls + 2 * NN;         // [N]
    float* out_h   = out_cls + 3 * NN;         // [N,32]

    // K0: weight prepacks + attn consts + cursor zero-init
    k0_prep<<<19, 256, 0, stream>>>(W1, W2, We1, ae1, We2, ae2,
                                    W1hi, W1lo, W2hi, W2lo, consts, bucketCursor);
    // stage1: padded-bucket bin + easum (28KB LDS, homogeneous)
    stage1_kernel<<<S1_B, 256, 0, stream>>>(ei, ea, bucketCursor, Apack, consts);
    // gemm1 + fused al1 (zero LDS -> full occupancy)
    gemm1_al1<<<G1_B, 256, 0, stream>>>(x, W1hi, W1lo, as1, ad1, als1, ald1, xs1b);
    // stage2: per-bucket counting sort -> indptr/degv/edgedat (+ ea_mean finalize)
    stage2_kernel<<<NBKT, 1024, 0, stream>>>(bucketCursor, Apack, indptr, degv,
                                             edgedat, consts);
    // gat1 + gemm2 fused: h1 stays in LDS; writes xs2b/als2/ald2 directly
    gat1_gemm2<<<NN / 8, 256, 0, stream>>>(xs1b, als1, ald1, edgedat, indptr, degv,
                                           consts, b1, g1, be1, W2hi, W2lo, as2, ad2,
                                           xs2b, als2, ald2);
    gat2_agg<<<NN / 4, 256, 0, stream>>>(xs2b, als2, ald2, edgedat, indptr, degv,
                                         consts, b2, g2, be2, Wc1, bc1, Wc2, bc2,
                                         Wr1, br1, Wr2, br2, out_h, out_cls, out_reg);
}

// Round 8
// 333.139 us; speedup vs baseline: 1.0226x; 1.0226x over previous
//
#include <hip/hip_runtime.h>
#include <cstdint>
#include <cstddef>

// ---------------- problem constants ----------------
#define NN 50000
#define EE 1600000
#define IN_DIM 256
#define HC 128      // HEADS*C
#define CD 32       // C
#define BN_RS 0.9999950000374997f  // 1/sqrt(1+1e-5)

#define CAP1 96     // deg ~ Poisson(32): P(deg>96) ~ 0 -> spill path is cold
#define CAP2 128
#define NBKT 196        // ceil(NN/256) buckets of 256 dst nodes
#define S1_B 782        // (EE+2047)/2048
#define HIST_B 320
#define G1_B 782        // gemm1 blocks (4 waves x 16 rows)

typedef __attribute__((ext_vector_type(8))) short short8;   // 8 bf16 (bit pattern)
typedef __attribute__((ext_vector_type(4))) float f32x4;

// ---------------- small helpers ----------------
__device__ __forceinline__ float lrelu(float a) { return a > 0.f ? a : 0.2f * a; }
__device__ __forceinline__ float elu(float a) { return a > 0.f ? a : (__expf(a) - 1.f); }

__device__ __forceinline__ unsigned short f2bf(float f) {
    unsigned int u = __float_as_uint(f);
    unsigned int r = (u + 0x7FFFu + ((u >> 16) & 1u)) >> 16;
    return (unsigned short)r;
}
__device__ __forceinline__ float bf2f(unsigned short b) {
    return __uint_as_float(((unsigned int)b) << 16);
}
__device__ __forceinline__ float2 bf2f2(unsigned int p) {
    float2 r;
    r.x = __uint_as_float(p << 16);
    r.y = __uint_as_float(p & 0xFFFF0000u);
    return r;
}
__device__ __forceinline__ void unpack_edge(unsigned long long p, int& s, float& eav) {
    s = (int)(unsigned int)(p & 0xFFFFFFFFull);
    eav = __uint_as_float((unsigned int)(p >> 32));
}
// select one of 4 by runtime index without scratch-spilling arrays (rule #20)
__device__ __forceinline__ float pick4(float a, float b, float c, float d, int h) {
    return (h & 2) ? ((h & 1) ? d : c) : ((h & 1) ? b : a);
}

// 256-thread exclusive scan (ONE internal barrier; all 256 must call)
__device__ __forceinline__ int block_excl_scan_256(int v, int tid, int* wsum) {
    int lane = tid & 63, wv = tid >> 6;
    int x = v;
    #pragma unroll
    for (int off = 1; off < 64; off <<= 1) {
        int y = __shfl_up(x, off);
        if (lane >= off) x += y;
    }
    if (lane == 63) wsum[wv] = x;
    __syncthreads();
    int wpre = 0;
    #pragma unroll
    for (int w = 0; w < 4; w++)
        if (w < wv) wpre += wsum[w];
    return wpre + x - v;
}

// ---------------- K0: W1/W2 frag prepack + attn consts + zero-init ----------------
__global__ __launch_bounds__(256) void k0_prep(const float* __restrict__ W1,
                                               const float* __restrict__ W2,
                                               const float* __restrict__ We1,
                                               const float* __restrict__ ae1,
                                               const float* __restrict__ We2,
                                               const float* __restrict__ ae2,
                                               unsigned short* __restrict__ W1hi,
                                               unsigned short* __restrict__ W1lo,
                                               unsigned short* __restrict__ W2hi,
                                               unsigned short* __restrict__ W2lo,
                                               float* __restrict__ consts,
                                               int* __restrict__ bucketHist) {
    int blk = blockIdx.x;
    int tid = threadIdx.x;
    if (blk < 16) {
        // W1 [256,128] -> frag order ((nt*8+kt)*64+lane)*8+j, split hi/lo
        int t = blk * 256 + tid;
        int lane = t & 63;
        int kt = (t >> 6) & 7;
        int nt = t >> 9;
        int kbase = kt * 32 + (lane >> 4) * 8;
        int col = nt * 16 + (lane & 15);
        size_t obase = (size_t)t * 8;
        #pragma unroll
        for (int j = 0; j < 8; j++) {
            float w = W1[(size_t)(kbase + j) * HC + col];
            unsigned short h = f2bf(w);
            W1hi[obase + j] = h;
            W1lo[obase + j] = f2bf(w - bf2f(h));
        }
    } else if (blk < 18) {
        // W2 [128,32] -> frag order ((nt*4+kt)*64+lane)*8+j, split hi/lo
        int t = (blk - 16) * 256 + tid;  // 0..511
        int lane = t & 63;
        int kt = (t >> 6) & 3;
        int nt = t >> 8;
        int kbase = kt * 32 + (lane >> 4) * 8;
        int col = nt * 16 + (lane & 15);
        size_t obase = (size_t)t * 8;
        #pragma unroll
        for (int j = 0; j < 8; j++) {
            float w = W2[(size_t)(kbase + j) * CD + col];
            unsigned short h = f2bf(w);
            W2hi[obase + j] = h;
            W2lo[obase + j] = f2bf(w - bf2f(h));
        }
    } else {
        if (tid < NBKT) bucketHist[tid] = 0;
        if (tid == 200) consts[0] = 0.f;     // easum accumulator
        if (tid < 4) {
            float s = 0.f;
            for (int c = 0; c < 32; c++) s += We1[tid * 32 + c] * ae1[tid * 32 + c];
            consts[2 + tid] = s;
        } else if (tid == 4) {
            float s = 0.f;
            for (int c = 0; c < 32; c++) s += We2[c] * ae2[c];
            consts[6] = s;
        }
    }
}

// ---------------- K_A: hist (LDS) || gemm1 (MFMA split-bf16 + fused al1) ----------
// al1 epilogue computes als1/ald1 straight from the MFMA accumulators (no re-read).
__global__ __launch_bounds__(256) void kA_hist_gemm1(const int* __restrict__ ei,
                                                     const float* __restrict__ ea,
                                                     const float* __restrict__ x,
                                                     const unsigned short* __restrict__ Whi,
                                                     const unsigned short* __restrict__ Wlo,
                                                     int* __restrict__ bucketHist,
                                                     float* __restrict__ easum,
                                                     const float* __restrict__ as1,
                                                     const float* __restrict__ ad1,
                                                     float* __restrict__ als,
                                                     float* __restrict__ ald,
                                                     unsigned short* __restrict__ xs1b) {
    __shared__ int h[256];
    int tid = threadIdx.x;
    if (blockIdx.x < HIST_B) {
        h[tid] = 0;
        __syncthreads();
        float s = 0.f;
        for (int i = blockIdx.x * 256 + tid; i < EE; i += HIST_B * 256) {
            atomicAdd(&h[ei[EE + i] >> 8], 1);
            s += ea[i];
        }
        __syncthreads();
        if (tid < NBKT && h[tid] > 0) atomicAdd(&bucketHist[tid], h[tid]);
        #pragma unroll
        for (int off = 32; off > 0; off >>= 1) s += __shfl_xor(s, off);
        if ((tid & 63) == 0) atomicAdd(easum, s);
    } else {
        int lane = tid & 63, wv = tid >> 6;
        int row0 = (blockIdx.x - HIST_B) * 64 + wv * 16;
        if (row0 >= NN) return;
        int m = lane & 15;
        int q = lane >> 4;
        f32x4 acc[8];
        #pragma unroll
        for (int nt = 0; nt < 8; nt++) acc[nt] = {0.f, 0.f, 0.f, 0.f};
        const float* xrow = x + (size_t)(row0 + m) * IN_DIM + q * 8;
        #pragma unroll
        for (int kt = 0; kt < 8; kt++) {
            float4 v0 = *(const float4*)(xrow + kt * 32);
            float4 v1 = *(const float4*)(xrow + kt * 32 + 4);
            float vv[8] = {v0.x, v0.y, v0.z, v0.w, v1.x, v1.y, v1.z, v1.w};
            short8 ahi, alo;
            #pragma unroll
            for (int j = 0; j < 8; j++) {
                unsigned short hh = f2bf(vv[j]);
                ahi[j] = (short)hh;
                alo[j] = (short)f2bf(vv[j] - bf2f(hh));
            }
            #pragma unroll
            for (int nt = 0; nt < 8; nt++) {
                size_t fb = ((size_t)(nt * 8 + kt) * 64 + lane) * 8;
                short8 bhi = *(const short8*)(Whi + fb);
                short8 blo = *(const short8*)(Wlo + fb);
                acc[nt] = __builtin_amdgcn_mfma_f32_16x16x32_bf16(ahi, bhi, acc[nt], 0, 0, 0);
                acc[nt] = __builtin_amdgcn_mfma_f32_16x16x32_bf16(ahi, blo, acc[nt], 0, 0, 0);
                acc[nt] = __builtin_amdgcn_mfma_f32_16x16x32_bf16(alo, bhi, acc[nt], 0, 0, 0);
            }
        }
        #pragma unroll
        for (int nt = 0; nt < 8; nt++) {
            #pragma unroll
            for (int rg = 0; rg < 4; rg++) {
                int row = row0 + q * 4 + rg;
                xs1b[(size_t)row * HC + nt * 16 + m] = f2bf(acc[nt][rg]);
            }
        }
        // ---- fused al1: als/ald from accumulators (col nt*16+m; head h = cols h*32..+31)
        float a_s0[4], a_s1[4], a_d0[4], a_d1[4];
        #pragma unroll
        for (int hh = 0; hh < 4; hh++) {
            a_s0[hh] = as1[hh * 32 + m];
            a_s1[hh] = as1[hh * 32 + 16 + m];
            a_d0[hh] = ad1[hh * 32 + m];
            a_d1[hh] = ad1[hh * 32 + 16 + m];
        }
        #pragma unroll
        for (int rg = 0; rg < 4; rg++) {
            int row = row0 + q * 4 + rg;
            #pragma unroll
            for (int hh = 0; hh < 4; hh++) {
                float s = acc[2 * hh][rg] * a_s0[hh] + acc[2 * hh + 1][rg] * a_s1[hh];
                float d = acc[2 * hh][rg] * a_d0[hh] + acc[2 * hh + 1][rg] * a_d1[hh];
                #pragma unroll
                for (int off = 1; off < 16; off <<= 1) {
                    s += __shfl_xor(s, off);
                    d += __shfl_xor(d, off);
                }
                if (m == 0) {
                    als[(size_t)row * 4 + hh] = s;
                    ald[(size_t)row * 4 + hh] = d;
                }
            }
        }
    }
}

// ---------------- bucket scan: bases + cursors + sentinels + ea_mean ----------------
__global__ void bucket_scan(const int* __restrict__ bucketHist,
                            int* __restrict__ bucketBase,
                            int* __restrict__ bucketCursor,
                            int* __restrict__ indptr,
                            float* __restrict__ consts) {
    __shared__ int wsum[4];
    int tid = threadIdx.x;  // 256
    int v = (tid < NBKT) ? bucketHist[tid] : 0;
    int excl = block_excl_scan_256(v, tid, wsum);
    if (tid <= NBKT) bucketBase[tid] = (tid == NBKT) ? EE : excl;
    if (tid < NBKT) bucketCursor[tid] = excl;
    if (tid == 0) { indptr[NN] = EE; consts[1] = consts[0] / (float)EE; }
}

// ---------------- K_B: stage1 (bucket bin, packed 8B records) ---------------------
// record: w0 = src | (dst&255)<<24  (src<2^24, bucket implicit in position), w1 = ea
__global__ __launch_bounds__(256) void kB_stage1(const int* __restrict__ ei,
                                                 const float* __restrict__ ea,
                                                 int* __restrict__ bucketCursor,
                                                 uint2* __restrict__ Apack) {
    __shared__ int cnt[256];
    __shared__ int basel[256];
    __shared__ int gbase[256];
    __shared__ int wsum[4];
    __shared__ int sdst[2048];
    __shared__ int ssrc[2048];
    __shared__ float sea[2048];
    int tid = threadIdx.x;
    int base = blockIdx.x * 2048;
    cnt[tid] = 0;
    __syncthreads();
    int d[8], s[8], r[8], bk[8];
    float e[8];
    #pragma unroll
    for (int k = 0; k < 8; k++) {
        int i = base + k * 256 + tid;
        if (i < EE) {
            d[k] = ei[EE + i];
            s[k] = ei[i];
            e[k] = ea[i];
            bk[k] = d[k] >> 8;
            r[k] = atomicAdd(&cnt[bk[k]], 1);   // LDS returning atomic: cheap
        } else d[k] = -1;
    }
    __syncthreads();
    int v = cnt[tid];
    int excl = block_excl_scan_256(v, tid, wsum);
    basel[tid] = excl;
    if (tid < NBKT) gbase[tid] = atomicAdd(&bucketCursor[tid], v);
    __syncthreads();
    #pragma unroll
    for (int k = 0; k < 8; k++) {
        if (d[k] >= 0) {
            int slot = basel[bk[k]] + r[k];
            sdst[slot] = d[k];
            ssrc[slot] = s[k];
            sea[slot] = e[k];
        }
    }
    __syncthreads();
    int total = basel[255] + cnt[255];
    for (int slot = tid; slot < total; slot += 256) {
        int dd = sdst[slot];
        int b = dd >> 8;
        int pos = gbase[b] + (slot - basel[b]);
        Apack[pos] = make_uint2((unsigned int)ssrc[slot] | ((unsigned int)(dd & 255) << 24),
                                __float_as_uint(sea[slot]));
    }
}

// ---------------- stage2 (1024 threads): per-bucket counting sort -> indptr + edgedat ----
__global__ __launch_bounds__(1024) void stage2_kernel(const int* __restrict__ bucketBase,
                                                      const uint2* __restrict__ Apack,
                                                      int* __restrict__ indptr,
                                                      unsigned long long* __restrict__ edgedat) {
    __shared__ int cnt[256];
    __shared__ int dbase[256];
    int tid = threadIdx.x;
    int b = blockIdx.x;
    int start = bucketBase[b], end = bucketBase[b + 1];
    if (tid < 256) cnt[tid] = 0;
    __syncthreads();
    for (int i = start + tid; i < end; i += 1024) atomicAdd(&cnt[Apack[i].x >> 24], 1);
    __syncthreads();
    // exclusive scan of 256 bins by wave 0 (4 bins/lane)
    if (tid < 64) {
        int b4 = tid * 4;
        int c0 = cnt[b4], c1 = cnt[b4 + 1], c2 = cnt[b4 + 2], c3 = cnt[b4 + 3];
        int t = c0 + c1 + c2 + c3;
        int x = t;
        #pragma unroll
        for (int off = 1; off < 64; off <<= 1) {
            int y = __shfl_up(x, off);
            if (tid >= off) x += y;
        }
        int e0 = x - t;
        dbase[b4] = e0;
        dbase[b4 + 1] = e0 + c0;
        dbase[b4 + 2] = e0 + c0 + c1;
        dbase[b4 + 3] = e0 + c0 + c1 + c2;
    }
    __syncthreads();
    if (tid < 256) {
        int n = b * 256 + tid;
        if (n < NN) indptr[n] = start + dbase[tid];
        cnt[tid] = 0;          // reuse as per-dst cursor
    }
    __syncthreads();
    for (int i = start + tid; i < end; i += 1024) {
        uint2 p = Apack[i];
        int dl = p.x >> 24;
        int r = atomicAdd(&cnt[dl], 1);
        int pos = start + dbase[dl] + r;
        edgedat[pos] = (unsigned long long)(p.x & 0xFFFFFFu) |
                       ((unsigned long long)p.y << 32);
    }
}

// accumulate one gathered uint2 (4 bf16 cols) with raw weight ww
#define ACC4(vv, ww) { float2 p0_ = bf2f2((vv).x); float2 p1_ = bf2f2((vv).y); \
    acc0 += p0_.x * (ww); acc1 += p0_.y * (ww); acc2 += p1_.x * (ww); acc3 += p1_.y * (ww); }

// ---------------- conv1 aggregation + FUSED gemm2 (h1 never leaves the block) ------
#define H1P 136   // h1 LDS row pitch (ushorts): 272B = 16B-aligned, spreads banks
__global__ __launch_bounds__(256, 8) void gat1_gemm2(
    const unsigned short* __restrict__ xs1b, const float* __restrict__ als,
    const float* __restrict__ ald, const unsigned long long* __restrict__ edgedat,
    const int* __restrict__ indptr, const float* __restrict__ consts,
    const float* __restrict__ b1, const float* __restrict__ g1,
    const float* __restrict__ be1,
    const unsigned short* __restrict__ W2hi, const unsigned short* __restrict__ W2lo,
    const float* __restrict__ as2, const float* __restrict__ ad2,
    unsigned short* __restrict__ xs2b, float* __restrict__ als2,
    float* __restrict__ ald2) {
    __shared__ __align__(16) float exbuf[8][CAP1][4];
    __shared__ int srcbuf[8][CAP1];
    __shared__ __align__(16) unsigned short h1hi_s[8][H1P];
    __shared__ __align__(16) unsigned short h1lo_s[8][H1P];
    int tid = threadIdx.x;
    int l = tid & 31;            // lane within half-wave
    int nb = tid >> 5;           // node slot 0..7
    int n = blockIdx.x * 8 + nb;
    int start = indptr[n];
    int deg = indptr[n + 1] - start;
    float ea_mean = consts[1];
    float ce0 = consts[2], ce1 = consts[3], ce2 = consts[4], ce3 = consts[5];
    float4 a4d = *(const float4*)(ald + (size_t)n * 4);
    float4 a4s = *(const float4*)(als + (size_t)n * 4);
    float ex00 = __expf(lrelu(a4s.x + a4d.x + ea_mean * ce0));
    float ex01 = __expf(lrelu(a4s.y + a4d.y + ea_mean * ce1));
    float ex02 = __expf(lrelu(a4s.z + a4d.z + ea_mean * ce2));
    float ex03 = __expf(lrelu(a4s.w + a4d.w + ea_mean * ce3));
    float sm0 = 0.f, sm1 = 0.f, sm2 = 0.f, sm3 = 0.f;
    const unsigned long long* edp = edgedat + start;
    // phase 1: raw exp weights -> LDS, per-head partial sums
    for (int i = l; i < deg; i += 32) {
        int s; float eav;
        unpack_edge(edp[i], s, eav);
        float4 v4 = *(const float4*)(als + (size_t)s * 4);
        float4 ex4;
        ex4.x = __expf(lrelu(v4.x + a4d.x + eav * ce0)); sm0 += ex4.x;
        ex4.y = __expf(lrelu(v4.y + a4d.y + eav * ce1)); sm1 += ex4.y;
        ex4.z = __expf(lrelu(v4.z + a4d.z + eav * ce2)); sm2 += ex4.z;
        ex4.w = __expf(lrelu(v4.w + a4d.w + eav * ce3)); sm3 += ex4.w;
        if (i < CAP1) {
            srcbuf[nb][i] = s * (HC * 2);                   // byte offset of src row
            *(float4*)(&exbuf[nb][i][0]) = ex4;
        }
    }
    #pragma unroll
    for (int off = 16; off > 0; off >>= 1) {
        sm0 += __shfl_xor(sm0, off);
        sm1 += __shfl_xor(sm1, off);
        sm2 += __shfl_xor(sm2, off);
        sm3 += __shfl_xor(sm3, off);
    }
    int h2 = l >> 3;                                         // this lane's head
    float ex0sel = pick4(ex00, ex01, ex02, ex03, h2);
    float inv = 1.0f / (pick4(sm0, sm1, sm2, sm3, h2) + ex0sel + 1e-16f);
    int mcap = deg < CAP1 ? deg : CAP1;
    const char* xb = (const char*)xs1b + (size_t)l * 8;      // lane's 4 cols (8B)
    float acc0, acc1, acc2, acc3;
    {   // self loop (raw weight)
        uint2 v = *(const uint2*)(xb + (size_t)n * (HC * 2));
        float2 p0 = bf2f2(v.x), p1 = bf2f2(v.y);
        acc0 = p0.x * ex0sel; acc1 = p0.y * ex0sel;
        acc2 = p1.x * ex0sel; acc3 = p1.y * ex0sel;
    }
    // phase 2: weighted gather, 8 loads in flight
    int i = 0;
    for (; i + 8 <= mcap; i += 8) {
        int o0 = srcbuf[nb][i + 0], o1 = srcbuf[nb][i + 1];
        int o2 = srcbuf[nb][i + 2], o3 = srcbuf[nb][i + 3];
        int o4 = srcbuf[nb][i + 4], o5 = srcbuf[nb][i + 5];
        int o6 = srcbuf[nb][i + 6], o7 = srcbuf[nb][i + 7];
        float w0 = exbuf[nb][i + 0][h2], w1 = exbuf[nb][i + 1][h2];
        float w2 = exbuf[nb][i + 2][h2], w3 = exbuf[nb][i + 3][h2];
        float w4 = exbuf[nb][i + 4][h2], w5 = exbuf[nb][i + 5][h2];
        float w6 = exbuf[nb][i + 6][h2], w7 = exbuf[nb][i + 7][h2];
        uint2 v0 = *(const uint2*)(xb + o0);
        uint2 v1 = *(const uint2*)(xb + o1);
        uint2 v2 = *(const uint2*)(xb + o2);
        uint2 v3 = *(const uint2*)(xb + o3);
        uint2 v4 = *(const uint2*)(xb + o4);
        uint2 v5 = *(const uint2*)(xb + o5);
        uint2 v6 = *(const uint2*)(xb + o6);
        uint2 v7 = *(const uint2*)(xb + o7);
        ACC4(v0, w0); ACC4(v1, w1); ACC4(v2, w2); ACC4(v3, w3);
        ACC4(v4, w4); ACC4(v5, w5); ACC4(v6, w6); ACC4(v7, w7);
    }
    for (; i < mcap; i++) {
        int o = srcbuf[nb][i];
        float w = exbuf[nb][i][h2];
        uint2 v = *(const uint2*)(xb + o);
        ACC4(v, w);
    }
    if (deg > CAP1) {   // spill fallback (deg > CAP1): recompute raw weights (cold)
        float aldsel = pick4(a4d.x, a4d.y, a4d.z, a4d.w, h2);
        float cesel = pick4(ce0, ce1, ce2, ce3, h2);
        for (int j = CAP1; j < deg; j++) {
            int s; float eav;
            unpack_edge(edp[j], s, eav);
            float w = __expf(lrelu(als[(size_t)s * 4 + h2] + aldsel + eav * cesel));
            uint2 v = *(const uint2*)(xb + (size_t)s * (HC * 2));
            ACC4(v, w);
        }
    }
    acc0 *= inv; acc1 *= inv; acc2 *= inv; acc3 *= inv;
    int c = l * 4;
    float4 bb = *(const float4*)(b1 + c);
    float4 gg = *(const float4*)(g1 + c);
    float4 eb = *(const float4*)(be1 + c);
    float o0 = elu((acc0 + bb.x) * (gg.x * BN_RS) + eb.x);
    float o1 = elu((acc1 + bb.y) * (gg.y * BN_RS) + eb.y);
    float o2 = elu((acc2 + bb.z) * (gg.z * BN_RS) + eb.z);
    float o3 = elu((acc3 + bb.w) * (gg.w * BN_RS) + eb.w);
    // split hi/lo bf16 into LDS for the fused gemm2
    unsigned short h0 = f2bf(o0), h1v = f2bf(o1), h2v = f2bf(o2), h3v = f2bf(o3);
    unsigned short l0 = f2bf(o0 - bf2f(h0)), l1 = f2bf(o1 - bf2f(h1v));
    unsigned short l2 = f2bf(o2 - bf2f(h2v)), l3 = f2bf(o3 - bf2f(h3v));
    uint2 hiw, low;
    hiw.x = (unsigned int)h0 | ((unsigned int)h1v << 16);
    hiw.y = (unsigned int)h2v | ((unsigned int)h3v << 16);
    low.x = (unsigned int)l0 | ((unsigned int)l1 << 16);
    low.y = (unsigned int)l2 | ((unsigned int)l3 << 16);
    *(uint2*)(&h1hi_s[nb][c]) = hiw;
    *(uint2*)(&h1lo_s[nb][c]) = low;
    __syncthreads();             // h1 tile complete
    if (tid >= 64) return;       // waves 1-3 done

    // ---- wave 0: gemm2 (16x16x32 MFMA) for rows n0..n0+7 ----
    int lane = tid;              // 0..63
    int m = lane & 15, q = lane >> 4;
    int r8 = m & 7;              // rows 8..15 duplicate 0..7 (outputs discarded)
    f32x4 g2acc0 = {0.f, 0.f, 0.f, 0.f};
    f32x4 g2acc1 = {0.f, 0.f, 0.f, 0.f};
    #pragma unroll
    for (int kt = 0; kt < 4; kt++) {
        short8 ahi = *(const short8*)(&h1hi_s[r8][q * 8 + kt * 32]);
        short8 alo = *(const short8*)(&h1lo_s[r8][q * 8 + kt * 32]);
        size_t fb0 = ((size_t)kt * 64 + lane) * 8;
        size_t fb1 = ((size_t)(4 + kt) * 64 + lane) * 8;
        short8 bhi0 = *(const short8*)(W2hi + fb0);
        short8 blo0 = *(const short8*)(W2lo + fb0);
        short8 bhi1 = *(const short8*)(W2hi + fb1);
        short8 blo1 = *(const short8*)(W2lo + fb1);
        g2acc0 = __builtin_amdgcn_mfma_f32_16x16x32_bf16(ahi, bhi0, g2acc0, 0, 0, 0);
        g2acc0 = __builtin_amdgcn_mfma_f32_16x16x32_bf16(ahi, blo0, g2acc0, 0, 0, 0);
        g2acc0 = __builtin_amdgcn_mfma_f32_16x16x32_bf16(alo, bhi0, g2acc0, 0, 0, 0);
        g2acc1 = __builtin_amdgcn_mfma_f32_16x16x32_bf16(ahi, bhi1, g2acc1, 0, 0, 0);
        g2acc1 = __builtin_amdgcn_mfma_f32_16x16x32_bf16(ahi, blo1, g2acc1, 0, 0, 0);
        g2acc1 = __builtin_amdgcn_mfma_f32_16x16x32_bf16(alo, bhi1, g2acc1, 0, 0, 0);
    }
    int n0 = blockIdx.x * 8;
    float a0 = as2[m], a1 = as2[m + 16];
    float d0 = ad2[m], d1 = ad2[m + 16];
    #pragma unroll
    for (int rg = 0; rg < 4; rg++) {
        int rloc = q * 4 + rg;       // 0..15; valid output rows are 0..7
        float s = g2acc0[rg] * a0 + g2acc1[rg] * a1;
        float d = g2acc0[rg] * d0 + g2acc1[rg] * d1;
        #pragma unroll
        for (int off = 1; off < 16; off <<= 1) {
            s += __shfl_xor(s, off);
            d += __shfl_xor(d, off);
        }
        if (rloc < 8) {
            int row = n0 + rloc;
            xs2b[(size_t)row * CD + m]      = f2bf(g2acc0[rg]);
            xs2b[(size_t)row * CD + 16 + m] = f2bf(g2acc1[rg]);
            if (m == 0) { als2[row] = s; ald2[row] = d; }
        }
    }
}

// ---------------- conv2 aggregation + fused MLP heads (raw-acc + post-scale) --------
__global__ __launch_bounds__(256) void gat2_agg(
    const unsigned short* __restrict__ xs2b, const float* __restrict__ als,
    const float* __restrict__ ald, const unsigned long long* __restrict__ edgedat,
    const int* __restrict__ indptr, const float* __restrict__ consts,
    const float* __restrict__ b2, const float* __restrict__ g2, const float* __restrict__ be2,
    const float* __restrict__ Wc1, const float* __restrict__ bc1,
    const float* __restrict__ Wc2, const float* __restrict__ bc2,
    const float* __restrict__ Wr1, const float* __restrict__ br1,
    const float* __restrict__ Wr2, const float* __restrict__ br2,
    float* __restrict__ hout, float* __restrict__ cls, float* __restrict__ reg) {
    __shared__ float exbuf[4][CAP2];
    __shared__ int srcbuf[4][CAP2];
    __shared__ __align__(16) float hbuf[4][32];
    int wv = threadIdx.x >> 6;
    int lane = threadIdx.x & 63;
    int n = blockIdx.x * 4 + wv;
    int start = indptr[n];
    int deg = indptr[n + 1] - start;
    float ea_mean = consts[1];
    float ce = consts[6];
    float aldn = ald[n];
    float ex0 = __expf(lrelu(als[n] + aldn + ea_mean * ce));
    float sm = 0.f;
    const unsigned long long* edp = edgedat + start;
    for (int i = lane; i < deg; i += 64) {
        int s; float eav;
        unpack_edge(edp[i], s, eav);
        float exv = __expf(lrelu(als[s] + aldn + eav * ce));
        if (i < CAP2) { srcbuf[wv][i] = s * (CD * 2); exbuf[wv][i] = exv; }
        sm += exv;
    }
    #pragma unroll
    for (int off = 32; off > 0; off >>= 1) sm += __shfl_xor(sm, off);
    float invd = 1.0f / (sm + ex0 + 1e-16f);
    int mcap = deg < CAP2 ? deg : CAP2;
    int oct = lane >> 3, lo = lane & 7;
    const char* xb = (const char*)xs2b + (size_t)lo * 8;     // lane's 4 cols (8B)
    float acc0 = 0.f, acc1 = 0.f, acc2 = 0.f, acc3 = 0.f;
    if (oct == 0) {   // self loop (raw weight), counted once after oct-reduce
        uint2 v = *(const uint2*)(xb + (size_t)n * (CD * 2));
        float2 p0 = bf2f2(v.x), p1 = bf2f2(v.y);
        acc0 = p0.x * ex0; acc1 = p0.y * ex0; acc2 = p1.x * ex0; acc3 = p1.y * ex0;
    }
    for (int i = oct; i < mcap; i += 8) {
        float w = exbuf[wv][i];
        int o = srcbuf[wv][i];
        uint2 v = *(const uint2*)(xb + o);
        ACC4(v, w);
    }
    for (int i = CAP2 + oct; i < deg; i += 8) {  // spill fallback (raw weights)
        int s; float eav;
        unpack_edge(edp[i], s, eav);
        float w = __expf(lrelu(als[s] + aldn + eav * ce));
        uint2 v = *(const uint2*)(xb + (size_t)s * (CD * 2));
        ACC4(v, w);
    }
    #pragma unroll
    for (int off = 8; off < 64; off <<= 1) {
        acc0 += __shfl_xor(acc0, off);
        acc1 += __shfl_xor(acc1, off);
        acc2 += __shfl_xor(acc2, off);
        acc3 += __shfl_xor(acc3, off);
    }
    if (lane < 8) {
        int c = lo * 4;
        float4 bb = *(const float4*)(b2 + c);
        float4 gg = *(const float4*)(g2 + c);
        float4 eb = *(const float4*)(be2 + c);
        float o0 = elu((acc0 * invd + bb.x) * (gg.x * BN_RS) + eb.x);
        float o1 = elu((acc1 * invd + bb.y) * (gg.y * BN_RS) + eb.y);
        float o2 = elu((acc2 * invd + bb.z) * (gg.z * BN_RS) + eb.z);
        float o3 = elu((acc3 * invd + bb.w) * (gg.w * BN_RS) + eb.w);
        *(float4*)(&hbuf[wv][c]) = make_float4(o0, o1, o2, o3);
        *(float4*)(hout + (size_t)n * CD + c) = make_float4(o0, o1, o2, o3);
    }
    // intra-wave LDS RAW: no block barrier needed (hbuf is per-wave)
    float r0 = 0.f, r1 = 0.f;
    if (lane < 32) {
        int j = lane & 15;
        bool iscls = lane < 16;
        float s = iscls ? bc1[j] : br1[j];
        #pragma unroll
        for (int cc = 0; cc < 32; cc++) {
            float w = iscls ? Wc1[cc * 16 + j] : Wr1[cc * 16 + j];
            s += hbuf[wv][cc] * w;
        }
        s = fmaxf(s, 0.f);
        if (iscls) { r0 = s * Wc2[j * 2]; r1 = s * Wc2[j * 2 + 1]; }
        else       { r0 = s * Wr2[j]; }
    }
    #pragma unroll
    for (int off = 1; off < 16; off <<= 1) {
        r0 += __shfl_xor(r0, off);
        r1 += __shfl_xor(r1, off);
    }
    if (lane == 0)  *(float2*)(cls + (size_t)n * 2) = make_float2(r0 + bc2[0], r1 + bc2[1]);
    if (lane == 16) reg[n] = r0 + br2[0];
}

// ---------------- launch ----------------
extern "C" void kernel_launch(void* const* d_in, const int* in_sizes, int n_in,
                              void* d_out, int out_size, void* d_ws, size_t ws_size,
                              hipStream_t stream) {
    const float* x   = (const float*)d_in[0];
    const int*   ei  = (const int*)d_in[1];
    const float* ea  = (const float*)d_in[2];
    const float* W1  = (const float*)d_in[3];
    const float* as1 = (const float*)d_in[4];
    const float* ad1 = (const float*)d_in[5];
    const float* We1 = (const float*)d_in[6];
    const float* ae1 = (const float*)d_in[7];
    const float* b1  = (const float*)d_in[8];
    const float* g1  = (const float*)d_in[9];
    const float* be1 = (const float*)d_in[10];
    const float* W2  = (const float*)d_in[11];
    const float* as2 = (const float*)d_in[12];
    const float* ad2 = (const float*)d_in[13];
    const float* We2 = (const float*)d_in[14];
    const float* ae2 = (const float*)d_in[15];
    const float* b2  = (const float*)d_in[16];
    const float* g2  = (const float*)d_in[17];
    const float* be2 = (const float*)d_in[18];
    const float* Wc1 = (const float*)d_in[19];
    const float* bc1 = (const float*)d_in[20];
    const float* Wc2 = (const float*)d_in[21];
    const float* bc2 = (const float*)d_in[22];
    const float* Wr1 = (const float*)d_in[23];
    const float* br1 = (const float*)d_in[24];
    const float* Wr2 = (const float*)d_in[25];
    const float* br2 = (const float*)d_in[26];

    char* ws = (char*)d_ws;
    unsigned short* xs1b = (unsigned short*)(ws + 0);          // N*128 bf16 = 12.8 MB
    uint2* Apack         = (uint2*)(ws + 12800000);            // E*8 = 12.8 MB (dead after stage2)
    unsigned short* xs2b = (unsigned short*)(ws + 38400000);   // N*32 bf16 = 3.2 MB
    float* als1          = (float*)(ws + 41600000);            // N*4
    float* ald1          = (float*)(ws + 42400000);            // N*4
    float* als2          = (float*)(ws + 43200000);            // N
    float* ald2          = (float*)(ws + 43400000);            // N
    float* consts        = (float*)(ws + 43600000);            // 8 floats
    int*   bucketHist    = (int*)(ws + 43600128);              // 196
    int*   bucketBase    = (int*)(ws + 43601024);              // 197
    int*   bucketCursor  = (int*)(ws + 43601920);              // 196
    int*   indptr        = (int*)(ws + 43602816);              // N+1
    unsigned long long* edgedat = (unsigned long long*)(ws + 43802824);  // E*8 -> ends 56602824
    unsigned short* W1hi = (unsigned short*)(ws + 56602832);   // 64 KB
    unsigned short* W1lo = (unsigned short*)(ws + 56668368);   // 64 KB
    unsigned short* W2hi = (unsigned short*)(ws + 56733904);   // 8 KB
    unsigned short* W2lo = (unsigned short*)(ws + 56742096);   // 8 KB (ends ~56.75 MB)

    float* out_cls = (float*)d_out;            // [N,2]
    float* out_reg = out_cls + 2 * NN;         // [N]
    float* out_h   = out_cls + 3 * NN;         // [N,32]

    // K0: weight prepacks + attn consts + zero-init (replaces memsets)
    k0_prep<<<19, 256, 0, stream>>>(W1, W2, We1, ae1, We2, ae2,
                                    W1hi, W1lo, W2hi, W2lo, consts, bucketHist);
    // K_A: hist || gemm1(+fused al1) — heterogeneous co-scheduled launch
    kA_hist_gemm1<<<HIST_B + G1_B, 256, 0, stream>>>(ei, ea, x, W1hi, W1lo,
                                                     bucketHist, consts,
                                                     as1, ad1, als1, ald1, xs1b);
    bucket_scan<<<1, 256, 0, stream>>>(bucketHist, bucketBase, bucketCursor, indptr, consts);
    // K_B: stage1 (packed 8B records)
    kB_stage1<<<S1_B, 256, 0, stream>>>(ei, ea, bucketCursor, Apack);
    // stage2: 1024 threads/block for full-machine occupancy at 196 blocks
    stage2_kernel<<<NBKT, 1024, 0, stream>>>(bucketBase, Apack, indptr, edgedat);

    // gat1 + gemm2 fused: h1 stays in LDS; writes xs2b/als2/ald2 directly
    gat1_gemm2<<<NN / 8, 256, 0, stream>>>(xs1b, als1, ald1, edgedat, indptr, consts,
                                           b1, g1, be1, W2hi, W2lo, as2, ad2,
                                           xs2b, als2, ald2);
    gat2_agg<<<NN / 4, 256, 0, stream>>>(xs2b, als2, ald2, edgedat, indptr, consts,
                                         b2, g2, be2, Wc1, bc1, Wc2, bc2,
                                         Wr1, br1, Wr2, br2, out_h, out_cls, out_reg);
}

// Round 9
// 324.983 us; speedup vs baseline: 1.0482x; 1.0251x over previous
//
#include <hip/hip_runtime.h>
#include <cstdint>
#include <cstddef>

// ---------------- problem constants ----------------
#define NN 50000
#define EE 1600000
#define IN_DIM 256
#define HC 128      // HEADS*C
#define CD 32       // C
#define BN_RS 0.9999950000374997f  // 1/sqrt(1+1e-5)

#define CAP1 96     // deg ~ Poisson(32): P(deg>96) ~ 0 -> spill path is cold
#define CAP2 128
#define NBKT 196        // ceil(NN/256) buckets of 256 dst nodes
#define S1_B 782        // (EE+2047)/2048
#define HIST_B 320
#define G1_B 782        // gemm1 blocks (4 waves x 16 rows)

typedef __attribute__((ext_vector_type(8))) short short8;   // 8 bf16 (bit pattern)
typedef __attribute__((ext_vector_type(4))) float f32x4;

// ---------------- small helpers ----------------
__device__ __forceinline__ float lrelu(float a) { return a > 0.f ? a : 0.2f * a; }
__device__ __forceinline__ float elu(float a) { return a > 0.f ? a : (__expf(a) - 1.f); }

__device__ __forceinline__ unsigned short f2bf(float f) {
    unsigned int u = __float_as_uint(f);
    unsigned int r = (u + 0x7FFFu + ((u >> 16) & 1u)) >> 16;
    return (unsigned short)r;
}
__device__ __forceinline__ float bf2f(unsigned short b) {
    return __uint_as_float(((unsigned int)b) << 16);
}
__device__ __forceinline__ float2 bf2f2(unsigned int p) {
    float2 r;
    r.x = __uint_as_float(p << 16);
    r.y = __uint_as_float(p & 0xFFFF0000u);
    return r;
}
__device__ __forceinline__ void unpack_edge(unsigned long long p, int& s, float& eav) {
    s = (int)(unsigned int)(p & 0xFFFFFFFFull);
    eav = __uint_as_float((unsigned int)(p >> 32));
}
// select one of 4 by runtime index without scratch-spilling arrays (rule #20)
__device__ __forceinline__ float pick4(float a, float b, float c, float d, int h) {
    return (h & 2) ? ((h & 1) ? d : c) : ((h & 1) ? b : a);
}

// 256-thread exclusive scan (ONE internal barrier; all 256 must call)
__device__ __forceinline__ int block_excl_scan_256(int v, int tid, int* wsum) {
    int lane = tid & 63, wv = tid >> 6;
    int x = v;
    #pragma unroll
    for (int off = 1; off < 64; off <<= 1) {
        int y = __shfl_up(x, off);
        if (lane >= off) x += y;
    }
    if (lane == 63) wsum[wv] = x;
    __syncthreads();
    int wpre = 0;
    #pragma unroll
    for (int w = 0; w < 4; w++)
        if (w < wv) wpre += wsum[w];
    return wpre + x - v;
}

// ---------------- K0: W1/W2 frag prepack + attn consts + zero-init ----------------
__global__ __launch_bounds__(256) void k0_prep(const float* __restrict__ W1,
                                               const float* __restrict__ W2,
                                               const float* __restrict__ We1,
                                               const float* __restrict__ ae1,
                                               const float* __restrict__ We2,
                                               const float* __restrict__ ae2,
                                               unsigned short* __restrict__ W1hi,
                                               unsigned short* __restrict__ W1lo,
                                               unsigned short* __restrict__ W2hi,
                                               unsigned short* __restrict__ W2lo,
                                               float* __restrict__ consts,
                                               int* __restrict__ bucketHist,
                                               int* __restrict__ bucketCursor,
                                               int* __restrict__ indptr) {
    int blk = blockIdx.x;
    int tid = threadIdx.x;
    if (blk < 16) {
        // W1 [256,128] -> frag order ((nt*8+kt)*64+lane)*8+j, split hi/lo
        int t = blk * 256 + tid;
        int lane = t & 63;
        int kt = (t >> 6) & 7;
        int nt = t >> 9;
        int kbase = kt * 32 + (lane >> 4) * 8;
        int col = nt * 16 + (lane & 15);
        size_t obase = (size_t)t * 8;
        #pragma unroll
        for (int j = 0; j < 8; j++) {
            float w = W1[(size_t)(kbase + j) * HC + col];
            unsigned short h = f2bf(w);
            W1hi[obase + j] = h;
            W1lo[obase + j] = f2bf(w - bf2f(h));
        }
    } else if (blk < 18) {
        // W2 [128,32] -> frag order ((nt*4+kt)*64+lane)*8+j, split hi/lo
        int t = (blk - 16) * 256 + tid;  // 0..511
        int lane = t & 63;
        int kt = (t >> 6) & 3;
        int nt = t >> 8;
        int kbase = kt * 32 + (lane >> 4) * 8;
        int col = nt * 16 + (lane & 15);
        size_t obase = (size_t)t * 8;
        #pragma unroll
        for (int j = 0; j < 8; j++) {
            float w = W2[(size_t)(kbase + j) * CD + col];
            unsigned short h = f2bf(w);
            W2hi[obase + j] = h;
            W2lo[obase + j] = f2bf(w - bf2f(h));
        }
    } else {
        if (tid < NBKT) { bucketHist[tid] = 0; bucketCursor[tid] = 0; }
        if (tid == 200) consts[0] = 0.f;     // easum accumulator
        if (tid == 201) indptr[NN] = EE;     // constant sentinel
        if (tid < 4) {
            float s = 0.f;
            for (int c = 0; c < 32; c++) s += We1[tid * 32 + c] * ae1[tid * 32 + c];
            consts[2 + tid] = s;
        } else if (tid == 4) {
            float s = 0.f;
            for (int c = 0; c < 32; c++) s += We2[c] * ae2[c];
            consts[6] = s;
        }
    }
}

// ---------------- K_A: hist (LDS) || gemm1 (MFMA split-bf16), fused ----------------
__global__ __launch_bounds__(256) void kA_hist_gemm1(const int* __restrict__ ei,
                                                     const float* __restrict__ ea,
                                                     const float* __restrict__ x,
                                                     const unsigned short* __restrict__ Whi,
                                                     const unsigned short* __restrict__ Wlo,
                                                     int* __restrict__ bucketHist,
                                                     float* __restrict__ easum,
                                                     unsigned short* __restrict__ xs1b) {
    __shared__ int h[256];
    int tid = threadIdx.x;
    if (blockIdx.x < HIST_B) {
        h[tid] = 0;
        __syncthreads();
        float s = 0.f;
        for (int i = blockIdx.x * 256 + tid; i < EE; i += HIST_B * 256) {
            atomicAdd(&h[ei[EE + i] >> 8], 1);
            s += ea[i];
        }
        __syncthreads();
        if (tid < NBKT && h[tid] > 0) atomicAdd(&bucketHist[tid], h[tid]);
        #pragma unroll
        for (int off = 32; off > 0; off >>= 1) s += __shfl_xor(s, off);
        if ((tid & 63) == 0) atomicAdd(easum, s);
    } else {
        int lane = tid & 63, wv = tid >> 6;
        int row0 = (blockIdx.x - HIST_B) * 64 + wv * 16;
        if (row0 >= NN) return;
        int m = lane & 15;
        int q = lane >> 4;
        f32x4 acc[8];
        #pragma unroll
        for (int nt = 0; nt < 8; nt++) acc[nt] = {0.f, 0.f, 0.f, 0.f};
        const float* xrow = x + (size_t)(row0 + m) * IN_DIM + q * 8;
        #pragma unroll
        for (int kt = 0; kt < 8; kt++) {
            float4 v0 = *(const float4*)(xrow + kt * 32);
            float4 v1 = *(const float4*)(xrow + kt * 32 + 4);
            float vv[8] = {v0.x, v0.y, v0.z, v0.w, v1.x, v1.y, v1.z, v1.w};
            short8 ahi, alo;
            #pragma unroll
            for (int j = 0; j < 8; j++) {
                unsigned short hh = f2bf(vv[j]);
                ahi[j] = (short)hh;
                alo[j] = (short)f2bf(vv[j] - bf2f(hh));
            }
            #pragma unroll
            for (int nt = 0; nt < 8; nt++) {
                size_t fb = ((size_t)(nt * 8 + kt) * 64 + lane) * 8;
                short8 bhi = *(const short8*)(Whi + fb);
                short8 blo = *(const short8*)(Wlo + fb);
                acc[nt] = __builtin_amdgcn_mfma_f32_16x16x32_bf16(ahi, bhi, acc[nt], 0, 0, 0);
                acc[nt] = __builtin_amdgcn_mfma_f32_16x16x32_bf16(ahi, blo, acc[nt], 0, 0, 0);
                acc[nt] = __builtin_amdgcn_mfma_f32_16x16x32_bf16(alo, bhi, acc[nt], 0, 0, 0);
            }
        }
        #pragma unroll
        for (int nt = 0; nt < 8; nt++) {
            #pragma unroll
            for (int rg = 0; rg < 4; rg++) {
                int row = row0 + q * 4 + rg;
                xs1b[(size_t)row * HC + nt * 16 + m] = f2bf(acc[nt][rg]);
            }
        }
    }
}

// ---------------- K_B: stage1 (bucket bin, packed 8B records) || al1, fused --------
// record: w0 = src | (dst&255)<<24  (src<2^24, bucket implicit in position), w1 = ea
// Each stage1 block computes the global bucket prefix from bucketHist itself
// (cursor starts at 0) — replaces the former single-block bucket_scan launch.
__global__ __launch_bounds__(256) void kB_stage1_al1(const int* __restrict__ ei,
                                                     const float* __restrict__ ea,
                                                     const int* __restrict__ bucketHist,
                                                     int* __restrict__ bucketCursor,
                                                     uint2* __restrict__ Apack,
                                                     const unsigned short* __restrict__ xs1b,
                                                     const float* __restrict__ as1,
                                                     const float* __restrict__ ad1,
                                                     float* __restrict__ als,
                                                     float* __restrict__ ald) {
    __shared__ int cnt[256];
    __shared__ int basel[256];
    __shared__ int gbase[256];
    __shared__ int wsum[4];
    __shared__ int wsum2[4];
    __shared__ int sdst[2048];
    __shared__ int ssrc[2048];
    __shared__ float sea[2048];
    int tid = threadIdx.x;
    if (blockIdx.x < S1_B) {
        cnt[tid] = 0;
        int hv = (tid < NBKT) ? bucketHist[tid] : 0;
        // internal barrier also publishes the cnt zeros
        int hexcl = block_excl_scan_256(hv, tid, wsum2);
        int base = blockIdx.x * 2048;
        int d[8], s[8], r[8], bk[8];
        float e[8];
        #pragma unroll
        for (int k = 0; k < 8; k++) {
            int i = base + k * 256 + tid;
            if (i < EE) {
                d[k] = ei[EE + i];
                s[k] = ei[i];
                e[k] = ea[i];
                bk[k] = d[k] >> 8;
                r[k] = atomicAdd(&cnt[bk[k]], 1);   // LDS returning atomic: cheap
            } else d[k] = -1;
        }
        __syncthreads();
        int v = cnt[tid];
        int excl = block_excl_scan_256(v, tid, wsum);
        basel[tid] = excl;
        if (tid < NBKT) gbase[tid] = hexcl + atomicAdd(&bucketCursor[tid], v);
        __syncthreads();
        #pragma unroll
        for (int k = 0; k < 8; k++) {
            if (d[k] >= 0) {
                int slot = basel[bk[k]] + r[k];
                sdst[slot] = d[k];
                ssrc[slot] = s[k];
                sea[slot] = e[k];
            }
        }
        __syncthreads();
        int total = basel[255] + cnt[255];
        for (int slot = tid; slot < total; slot += 256) {
            int dd = sdst[slot];
            int b = dd >> 8;
            int pos = gbase[b] + (slot - basel[b]);
            Apack[pos] = make_uint2((unsigned int)ssrc[slot] | ((unsigned int)(dd & 255) << 24),
                                    __float_as_uint(sea[slot]));
        }
    } else {
        // ---- al1 path: one thread per (node,head) — hidden next to stage1 blocks ----
        int t = (blockIdx.x - S1_B) * 256 + tid;
        if (t < NN * 4) {
            int hh = t & 3;
            const unsigned int* xp = (const unsigned int*)(xs1b + (size_t)t * 32);
            const float* ap = as1 + hh * 32;
            const float* dp = ad1 + hh * 32;
            float s = 0.f, d = 0.f;
            #pragma unroll
            for (int q = 0; q < 16; q++) {
                float2 v = bf2f2(xp[q]);
                s += v.x * ap[q * 2] + v.y * ap[q * 2 + 1];
                d += v.x * dp[q * 2] + v.y * dp[q * 2 + 1];
            }
            als[t] = s;
            ald[t] = d;
        }
    }
}

// ---------------- stage2 (1024 threads): per-bucket counting sort -> indptr + edgedat ----
// Computes its own bucket base from bucketHist (replaces bucket_scan's bucketBase).
__global__ __launch_bounds__(1024) void stage2_kernel(const int* __restrict__ bucketHist,
                                                      const uint2* __restrict__ Apack,
                                                      int* __restrict__ indptr,
                                                      unsigned long long* __restrict__ edgedat,
                                                      float* __restrict__ consts) {
    __shared__ int cnt[256];
    __shared__ int dbase[256];
    __shared__ int s_start;
    int tid = threadIdx.x;
    int b = blockIdx.x;
    if (b == 0 && tid == 0) consts[1] = consts[0] / (float)EE;  // ea_mean finalize
    if (tid < 64) {
        int p = 0;
        for (int i = tid; i < b; i += 64) p += bucketHist[i];
        #pragma unroll
        for (int off = 32; off > 0; off >>= 1) p += __shfl_xor(p, off);
        if (tid == 0) s_start = p;
    }
    if (tid < 256) cnt[tid] = 0;
    __syncthreads();
    int start = s_start;
    int end = start + bucketHist[b];
    for (int i = start + tid; i < end; i += 1024) atomicAdd(&cnt[Apack[i].x >> 24], 1);
    __syncthreads();
    // exclusive scan of 256 bins by wave 0 (4 bins/lane)
    if (tid < 64) {
        int b4 = tid * 4;
        int c0 = cnt[b4], c1 = cnt[b4 + 1], c2 = cnt[b4 + 2], c3 = cnt[b4 + 3];
        int t = c0 + c1 + c2 + c3;
        int x = t;
        #pragma unroll
        for (int off = 1; off < 64; off <<= 1) {
            int y = __shfl_up(x, off);
            if (tid >= off) x += y;
        }
        int e0 = x - t;
        dbase[b4] = e0;
        dbase[b4 + 1] = e0 + c0;
        dbase[b4 + 2] = e0 + c0 + c1;
        dbase[b4 + 3] = e0 + c0 + c1 + c2;
    }
    __syncthreads();
    if (tid < 256) {
        int n = b * 256 + tid;
        if (n < NN) indptr[n] = start + dbase[tid];
        cnt[tid] = 0;          // reuse as per-dst cursor
    }
    __syncthreads();
    for (int i = start + tid; i < end; i += 1024) {
        uint2 p = Apack[i];
        int dl = p.x >> 24;
        int r = atomicAdd(&cnt[dl], 1);
        int pos = start + dbase[dl] + r;
        edgedat[pos] = (unsigned long long)(p.x & 0xFFFFFFu) |
                       ((unsigned long long)p.y << 32);
    }
}

// accumulate one gathered uint2 (4 bf16 cols) with raw weight ww
#define ACC4(vv, ww) { float2 p0_ = bf2f2((vv).x); float2 p1_ = bf2f2((vv).y); \
    acc0 += p0_.x * (ww); acc1 += p0_.y * (ww); acc2 += p1_.x * (ww); acc3 += p1_.y * (ww); }

// ---------------- conv1 aggregation + FUSED gemm2 (h1 never leaves the block) ------
#define H1P 136   // h1 LDS row pitch (ushorts): 272B = 16B-aligned, spreads banks
__global__ __launch_bounds__(256, 8) void gat1_gemm2(
    const unsigned short* __restrict__ xs1b, const float* __restrict__ als,
    const float* __restrict__ ald, const unsigned long long* __restrict__ edgedat,
    const int* __restrict__ indptr, const float* __restrict__ consts,
    const float* __restrict__ b1, const float* __restrict__ g1,
    const float* __restrict__ be1,
    const unsigned short* __restrict__ W2hi, const unsigned short* __restrict__ W2lo,
    const float* __restrict__ as2, const float* __restrict__ ad2,
    unsigned short* __restrict__ xs2b, float* __restrict__ als2,
    float* __restrict__ ald2) {
    __shared__ __align__(16) float exbuf[8][CAP1][4];
    __shared__ int srcbuf[8][CAP1];
    __shared__ __align__(16) unsigned short h1hi_s[8][H1P];
    __shared__ __align__(16) unsigned short h1lo_s[8][H1P];
    int tid = threadIdx.x;
    int l = tid & 31;            // lane within half-wave
    int nb = tid >> 5;           // node slot 0..7
    int n = blockIdx.x * 8 + nb;
    int start = indptr[n];
    int deg = indptr[n + 1] - start;
    float ea_mean = consts[1];
    float ce0 = consts[2], ce1 = consts[3], ce2 = consts[4], ce3 = consts[5];
    float4 a4d = *(const float4*)(ald + (size_t)n * 4);
    float4 a4s = *(const float4*)(als + (size_t)n * 4);
    float ex00 = __expf(lrelu(a4s.x + a4d.x + ea_mean * ce0));
    float ex01 = __expf(lrelu(a4s.y + a4d.y + ea_mean * ce1));
    float ex02 = __expf(lrelu(a4s.z + a4d.z + ea_mean * ce2));
    float ex03 = __expf(lrelu(a4s.w + a4d.w + ea_mean * ce3));
    float sm0 = 0.f, sm1 = 0.f, sm2 = 0.f, sm3 = 0.f;
    const unsigned long long* edp = edgedat + start;
    // phase 1: raw exp weights -> LDS, per-head partial sums
    for (int i = l; i < deg; i += 32) {
        int s; float eav;
        unpack_edge(edp[i], s, eav);
        float4 v4 = *(const float4*)(als + (size_t)s * 4);
        float4 ex4;
        ex4.x = __expf(lrelu(v4.x + a4d.x + eav * ce0)); sm0 += ex4.x;
        ex4.y = __expf(lrelu(v4.y + a4d.y + eav * ce1)); sm1 += ex4.y;
        ex4.z = __expf(lrelu(v4.z + a4d.z + eav * ce2)); sm2 += ex4.z;
        ex4.w = __expf(lrelu(v4.w + a4d.w + eav * ce3)); sm3 += ex4.w;
        if (i < CAP1) {
            srcbuf[nb][i] = s * (HC * 2);                   // byte offset of src row
            *(float4*)(&exbuf[nb][i][0]) = ex4;
        }
    }
    #pragma unroll
    for (int off = 16; off > 0; off >>= 1) {
        sm0 += __shfl_xor(sm0, off);
        sm1 += __shfl_xor(sm1, off);
        sm2 += __shfl_xor(sm2, off);
        sm3 += __shfl_xor(sm3, off);
    }
    int h2 = l >> 3;                                         // this lane's head
    float ex0sel = pick4(ex00, ex01, ex02, ex03, h2);
    float inv = 1.0f / (pick4(sm0, sm1, sm2, sm3, h2) + ex0sel + 1e-16f);
    int mcap = deg < CAP1 ? deg : CAP1;
    const char* xb = (const char*)xs1b + (size_t)l * 8;      // lane's 4 cols (8B)
    float acc0, acc1, acc2, acc3;
    {   // self loop (raw weight)
        uint2 v = *(const uint2*)(xb + (size_t)n * (HC * 2));
        float2 p0 = bf2f2(v.x), p1 = bf2f2(v.y);
        acc0 = p0.x * ex0sel; acc1 = p0.y * ex0sel;
        acc2 = p1.x * ex0sel; acc3 = p1.y * ex0sel;
    }
    // phase 2: weighted gather, 8 loads in flight
    int i = 0;
    for (; i + 8 <= mcap; i += 8) {
        int o0 = srcbuf[nb][i + 0], o1 = srcbuf[nb][i + 1];
        int o2 = srcbuf[nb][i + 2], o3 = srcbuf[nb][i + 3];
        int o4 = srcbuf[nb][i + 4], o5 = srcbuf[nb][i + 5];
        int o6 = srcbuf[nb][i + 6], o7 = srcbuf[nb][i + 7];
        float w0 = exbuf[nb][i + 0][h2], w1 = exbuf[nb][i + 1][h2];
        float w2 = exbuf[nb][i + 2][h2], w3 = exbuf[nb][i + 3][h2];
        float w4 = exbuf[nb][i + 4][h2], w5 = exbuf[nb][i + 5][h2];
        float w6 = exbuf[nb][i + 6][h2], w7 = exbuf[nb][i + 7][h2];
        uint2 v0 = *(const uint2*)(xb + o0);
        uint2 v1 = *(const uint2*)(xb + o1);
        uint2 v2 = *(const uint2*)(xb + o2);
        uint2 v3 = *(const uint2*)(xb + o3);
        uint2 v4 = *(const uint2*)(xb + o4);
        uint2 v5 = *(const uint2*)(xb + o5);
        uint2 v6 = *(const uint2*)(xb + o6);
        uint2 v7 = *(const uint2*)(xb + o7);
        ACC4(v0, w0); ACC4(v1, w1); ACC4(v2, w2); ACC4(v3, w3);
        ACC4(v4, w4); ACC4(v5, w5); ACC4(v6, w6); ACC4(v7, w7);
    }
    for (; i < mcap; i++) {
        int o = srcbuf[nb][i];
        float w = exbuf[nb][i][h2];
        uint2 v = *(const uint2*)(xb + o);
        ACC4(v, w);
    }
    if (deg > CAP1) {   // spill fallback (deg > CAP1): recompute raw weights (cold)
        float aldsel = pick4(a4d.x, a4d.y, a4d.z, a4d.w, h2);
        float cesel = pick4(ce0, ce1, ce2, ce3, h2);
        for (int j = CAP1; j < deg; j++) {
            int s; float eav;
            unpack_edge(edp[j], s, eav);
            float w = __expf(lrelu(als[(size_t)s * 4 + h2] + aldsel + eav * cesel));
            uint2 v = *(const uint2*)(xb + (size_t)s * (HC * 2));
            ACC4(v, w);
        }
    }
    acc0 *= inv; acc1 *= inv; acc2 *= inv; acc3 *= inv;
    int c = l * 4;
    float4 bb = *(const float4*)(b1 + c);
    float4 gg = *(const float4*)(g1 + c);
    float4 eb = *(const float4*)(be1 + c);
    float o0 = elu((acc0 + bb.x) * (gg.x * BN_RS) + eb.x);
    float o1 = elu((acc1 + bb.y) * (gg.y * BN_RS) + eb.y);
    float o2 = elu((acc2 + bb.z) * (gg.z * BN_RS) + eb.z);
    float o3 = elu((acc3 + bb.w) * (gg.w * BN_RS) + eb.w);
    // split hi/lo bf16 into LDS for the fused gemm2
    unsigned short h0 = f2bf(o0), h1v = f2bf(o1), h2v = f2bf(o2), h3v = f2bf(o3);
    unsigned short l0 = f2bf(o0 - bf2f(h0)), l1 = f2bf(o1 - bf2f(h1v));
    unsigned short l2 = f2bf(o2 - bf2f(h2v)), l3 = f2bf(o3 - bf2f(h3v));
    uint2 hiw, low;
    hiw.x = (unsigned int)h0 | ((unsigned int)h1v << 16);
    hiw.y = (unsigned int)h2v | ((unsigned int)h3v << 16);
    low.x = (unsigned int)l0 | ((unsigned int)l1 << 16);
    low.y = (unsigned int)l2 | ((unsigned int)l3 << 16);
    *(uint2*)(&h1hi_s[nb][c]) = hiw;
    *(uint2*)(&h1lo_s[nb][c]) = low;
    __syncthreads();             // h1 tile complete
    if (tid >= 64) return;       // waves 1-3 done

    // ---- wave 0: gemm2 (16x16x32 MFMA) for rows n0..n0+7 ----
    int lane = tid;              // 0..63
    int m = lane & 15, q = lane >> 4;
    int r8 = m & 7;              // rows 8..15 duplicate 0..7 (outputs discarded)
    f32x4 g2acc0 = {0.f, 0.f, 0.f, 0.f};
    f32x4 g2acc1 = {0.f, 0.f, 0.f, 0.f};
    #pragma unroll
    for (int kt = 0; kt < 4; kt++) {
        short8 ahi = *(const short8*)(&h1hi_s[r8][q * 8 + kt * 32]);
        short8 alo = *(const short8*)(&h1lo_s[r8][q * 8 + kt * 32]);
        size_t fb0 = ((size_t)kt * 64 + lane) * 8;
        size_t fb1 = ((size_t)(4 + kt) * 64 + lane) * 8;
        short8 bhi0 = *(const short8*)(W2hi + fb0);
        short8 blo0 = *(const short8*)(W2lo + fb0);
        short8 bhi1 = *(const short8*)(W2hi + fb1);
        short8 blo1 = *(const short8*)(W2lo + fb1);
        g2acc0 = __builtin_amdgcn_mfma_f32_16x16x32_bf16(ahi, bhi0, g2acc0, 0, 0, 0);
        g2acc0 = __builtin_amdgcn_mfma_f32_16x16x32_bf16(ahi, blo0, g2acc0, 0, 0, 0);
        g2acc0 = __builtin_amdgcn_mfma_f32_16x16x32_bf16(alo, bhi0, g2acc0, 0, 0, 0);
        g2acc1 = __builtin_amdgcn_mfma_f32_16x16x32_bf16(ahi, bhi1, g2acc1, 0, 0, 0);
        g2acc1 = __builtin_amdgcn_mfma_f32_16x16x32_bf16(ahi, blo1, g2acc1, 0, 0, 0);
        g2acc1 = __builtin_amdgcn_mfma_f32_16x16x32_bf16(alo, bhi1, g2acc1, 0, 0, 0);
    }
    int n0 = blockIdx.x * 8;
    float a0 = as2[m], a1 = as2[m + 16];
    float d0 = ad2[m], d1 = ad2[m + 16];
    #pragma unroll
    for (int rg = 0; rg < 4; rg++) {
        int rloc = q * 4 + rg;       // 0..15; valid output rows are 0..7
        float s = g2acc0[rg] * a0 + g2acc1[rg] * a1;
        float d = g2acc0[rg] * d0 + g2acc1[rg] * d1;
        #pragma unroll
        for (int off = 1; off < 16; off <<= 1) {
            s += __shfl_xor(s, off);
            d += __shfl_xor(d, off);
        }
        if (rloc < 8) {
            int row = n0 + rloc;
            xs2b[(size_t)row * CD + m]      = f2bf(g2acc0[rg]);
            xs2b[(size_t)row * CD + 16 + m] = f2bf(g2acc1[rg]);
            if (m == 0) { als2[row] = s; ald2[row] = d; }
        }
    }
}

// ---------------- conv2 aggregation + fused MLP heads (raw-acc + post-scale) --------
__global__ __launch_bounds__(256) void gat2_agg(
    const unsigned short* __restrict__ xs2b, const float* __restrict__ als,
    const float* __restrict__ ald, const unsigned long long* __restrict__ edgedat,
    const int* __restrict__ indptr, const float* __restrict__ consts,
    const float* __restrict__ b2, const float* __restrict__ g2, const float* __restrict__ be2,
    const float* __restrict__ Wc1, const float* __restrict__ bc1,
    const float* __restrict__ Wc2, const float* __restrict__ bc2,
    const float* __restrict__ Wr1, const float* __restrict__ br1,
    const float* __restrict__ Wr2, const float* __restrict__ br2,
    float* __restrict__ hout, float* __restrict__ cls, float* __restrict__ reg) {
    __shared__ float exbuf[4][CAP2];
    __shared__ int srcbuf[4][CAP2];
    __shared__ __align__(16) float hbuf[4][32];
    int wv = threadIdx.x >> 6;
    int lane = threadIdx.x & 63;
    int n = blockIdx.x * 4 + wv;
    int start = indptr[n];
    int deg = indptr[n + 1] - start;
    float ea_mean = consts[1];
    float ce = consts[6];
    float aldn = ald[n];
    float ex0 = __expf(lrelu(als[n] + aldn + ea_mean * ce));
    float sm = 0.f;
    const unsigned long long* edp = edgedat + start;
    for (int i = lane; i < deg; i += 64) {
        int s; float eav;
        unpack_edge(edp[i], s, eav);
        float exv = __expf(lrelu(als[s] + aldn + eav * ce));
        if (i < CAP2) { srcbuf[wv][i] = s * (CD * 2); exbuf[wv][i] = exv; }
        sm += exv;
    }
    #pragma unroll
    for (int off = 32; off > 0; off >>= 1) sm += __shfl_xor(sm, off);
    float invd = 1.0f / (sm + ex0 + 1e-16f);
    int mcap = deg < CAP2 ? deg : CAP2;
    int oct = lane >> 3, lo = lane & 7;
    const char* xb = (const char*)xs2b + (size_t)lo * 8;     // lane's 4 cols (8B)
    float acc0 = 0.f, acc1 = 0.f, acc2 = 0.f, acc3 = 0.f;
    if (oct == 0) {   // self loop (raw weight), counted once after oct-reduce
        uint2 v = *(const uint2*)(xb + (size_t)n * (CD * 2));
        float2 p0 = bf2f2(v.x), p1 = bf2f2(v.y);
        acc0 = p0.x * ex0; acc1 = p0.y * ex0; acc2 = p1.x * ex0; acc3 = p1.y * ex0;
    }
    for (int i = oct; i < mcap; i += 8) {
        float w = exbuf[wv][i];
        int o = srcbuf[wv][i];
        uint2 v = *(const uint2*)(xb + o);
        ACC4(v, w);
    }
    for (int i = CAP2 + oct; i < deg; i += 8) {  // spill fallback (raw weights)
        int s; float eav;
        unpack_edge(edp[i], s, eav);
        float w = __expf(lrelu(als[s] + aldn + eav * ce));
        uint2 v = *(const uint2*)(xb + (size_t)s * (CD * 2));
        ACC4(v, w);
    }
    #pragma unroll
    for (int off = 8; off < 64; off <<= 1) {
        acc0 += __shfl_xor(acc0, off);
        acc1 += __shfl_xor(acc1, off);
        acc2 += __shfl_xor(acc2, off);
        acc3 += __shfl_xor(acc3, off);
    }
    if (lane < 8) {
        int c = lo * 4;
        float4 bb = *(const float4*)(b2 + c);
        float4 gg = *(const float4*)(g2 + c);
        float4 eb = *(const float4*)(be2 + c);
        float o0 = elu((acc0 * invd + bb.x) * (gg.x * BN_RS) + eb.x);
        float o1 = elu((acc1 * invd + bb.y) * (gg.y * BN_RS) + eb.y);
        float o2 = elu((acc2 * invd + bb.z) * (gg.z * BN_RS) + eb.z);
        float o3 = elu((acc3 * invd + bb.w) * (gg.w * BN_RS) + eb.w);
        *(float4*)(&hbuf[wv][c]) = make_float4(o0, o1, o2, o3);
        *(float4*)(hout + (size_t)n * CD + c) = make_float4(o0, o1, o2, o3);
    }
    // intra-wave LDS RAW: no block barrier needed (hbuf is per-wave)
    float r0 = 0.f, r1 = 0.f;
    if (lane < 32) {
        int j = lane & 15;
        bool iscls = lane < 16;
        float s = iscls ? bc1[j] : br1[j];
        #pragma unroll
        for (int cc = 0; cc < 32; cc++) {
            float w = iscls ? Wc1[cc * 16 + j] : Wr1[cc * 16 + j];
            s += hbuf[wv][cc] * w;
        }
        s = fmaxf(s, 0.f);
        if (iscls) { r0 = s * Wc2[j * 2]; r1 = s * Wc2[j * 2 + 1]; }
        else       { r0 = s * Wr2[j]; }
    }
    #pragma unroll
    for (int off = 1; off < 16; off <<= 1) {
        r0 += __shfl_xor(r0, off);
        r1 += __shfl_xor(r1, off);
    }
    if (lane == 0)  *(float2*)(cls + (size_t)n * 2) = make_float2(r0 + bc2[0], r1 + bc2[1]);
    if (lane == 16) reg[n] = r0 + br2[0];
}

// ---------------- launch ----------------
extern "C" void kernel_launch(void* const* d_in, const int* in_sizes, int n_in,
                              void* d_out, int out_size, void* d_ws, size_t ws_size,
                              hipStream_t stream) {
    const float* x   = (const float*)d_in[0];
    const int*   ei  = (const int*)d_in[1];
    const float* ea  = (const float*)d_in[2];
    const float* W1  = (const float*)d_in[3];
    const float* as1 = (const float*)d_in[4];
    const float* ad1 = (const float*)d_in[5];
    const float* We1 = (const float*)d_in[6];
    const float* ae1 = (const float*)d_in[7];
    const float* b1  = (const float*)d_in[8];
    const float* g1  = (const float*)d_in[9];
    const float* be1 = (const float*)d_in[10];
    const float* W2  = (const float*)d_in[11];
    const float* as2 = (const float*)d_in[12];
    const float* ad2 = (const float*)d_in[13];
    const float* We2 = (const float*)d_in[14];
    const float* ae2 = (const float*)d_in[15];
    const float* b2  = (const float*)d_in[16];
    const float* g2  = (const float*)d_in[17];
    const float* be2 = (const float*)d_in[18];
    const float* Wc1 = (const float*)d_in[19];
    const float* bc1 = (const float*)d_in[20];
    const float* Wc2 = (const float*)d_in[21];
    const float* bc2 = (const float*)d_in[22];
    const float* Wr1 = (const float*)d_in[23];
    const float* br1 = (const float*)d_in[24];
    const float* Wr2 = (const float*)d_in[25];
    const float* br2 = (const float*)d_in[26];

    char* ws = (char*)d_ws;
    unsigned short* xs1b = (unsigned short*)(ws + 0);          // N*128 bf16 = 12.8 MB
    uint2* Apack         = (uint2*)(ws + 12800000);            // E*8 = 12.8 MB (dead after stage2)
    unsigned short* xs2b = (unsigned short*)(ws + 38400000);   // N*32 bf16 = 3.2 MB
    float* als1          = (float*)(ws + 41600000);            // N*4
    float* ald1          = (float*)(ws + 42400000);            // N*4
    float* als2          = (float*)(ws + 43200000);            // N
    float* ald2          = (float*)(ws + 43400000);            // N
    float* consts        = (float*)(ws + 43600000);            // 8 floats
    int*   bucketHist    = (int*)(ws + 43600128);              // 196
    int*   bucketCursor  = (int*)(ws + 43601920);              // 196
    int*   indptr        = (int*)(ws + 43602816);              // N+1
    unsigned long long* edgedat = (unsigned long long*)(ws + 43802824);  // E*8 -> ends 56602824
    unsigned short* W1hi = (unsigned short*)(ws + 56602832);   // 64 KB
    unsigned short* W1lo = (unsigned short*)(ws + 56668368);   // 64 KB
    unsigned short* W2hi = (unsigned short*)(ws + 56733904);   // 8 KB
    unsigned short* W2lo = (unsigned short*)(ws + 56742096);   // 8 KB (ends ~56.75 MB)

    float* out_cls = (float*)d_out;            // [N,2]
    float* out_reg = out_cls + 2 * NN;         // [N]
    float* out_h   = out_cls + 3 * NN;         // [N,32]

    // K0: weight prepacks + attn consts + zero-init (hist, cursors) + indptr sentinel
    k0_prep<<<19, 256, 0, stream>>>(W1, W2, We1, ae1, We2, ae2,
                                    W1hi, W1lo, W2hi, W2lo, consts,
                                    bucketHist, bucketCursor, indptr);
    // K_A: hist || gemm1 — heterogeneous co-scheduled launch (r4 pairing)
    kA_hist_gemm1<<<HIST_B + G1_B, 256, 0, stream>>>(ei, ea, x, W1hi, W1lo,
                                                     bucketHist, consts, xs1b);
    // K_B: stage1 (per-block bucket prefix, packed 8B records) || al1 (hidden)
    kB_stage1_al1<<<S1_B + 782, 256, 0, stream>>>(ei, ea, bucketHist, bucketCursor,
                                                  Apack, xs1b, as1, ad1, als1, ald1);
    // stage2: per-bucket counting sort -> indptr + edgedat (+ ea_mean finalize)
    stage2_kernel<<<NBKT, 1024, 0, stream>>>(bucketHist, Apack, indptr, edgedat, consts);

    // gat1 + gemm2 fused: h1 stays in LDS; writes xs2b/als2/ald2 directly
    gat1_gemm2<<<NN / 8, 256, 0, stream>>>(xs1b, als1, ald1, edgedat, indptr, consts,
                                           b1, g1, be1, W2hi, W2lo, as2, ad2,
                                           xs2b, als2, ald2);
    gat2_agg<<<NN / 4, 256, 0, stream>>>(xs2b, als2, ald2, edgedat, indptr, consts,
                                         b2, g2, be2, Wc1, bc1, Wc2, bc2,
                                         Wr1, br1, Wr2, br2, out_h, out_cls, out_reg);
}

// Round 10
// 315.504 us; speedup vs baseline: 1.0797x; 1.0300x over previous
//
#include <hip/hip_runtime.h>
#include <cstdint>
#include <cstddef>

// ---------------- problem constants ----------------
#define NN 50000
#define EE 1600000
#define IN_DIM 256
#define HC 128      // HEADS*C
#define CD 32       // C
#define BN_RS 0.9999950000374997f  // 1/sqrt(1+1e-5)

#define CAP1 96     // deg ~ Poisson(32): P(deg>96) ~ 0 -> spill path is cold
#define CAP2 128
#define NBKT 196        // ceil(NN/256) buckets of 256 dst nodes
#define S1_B 782        // (EE+2047)/2048
#define HIST_B 320
#define G1_B 782        // gemm1 blocks (4 waves x 16 rows)

typedef __attribute__((ext_vector_type(8))) short short8;   // 8 bf16 (bit pattern)
typedef __attribute__((ext_vector_type(4))) float f32x4;

// ---------------- small helpers ----------------
__device__ __forceinline__ float lrelu(float a) { return a > 0.f ? a : 0.2f * a; }
__device__ __forceinline__ float elu(float a) { return a > 0.f ? a : (__expf(a) - 1.f); }

__device__ __forceinline__ unsigned short f2bf(float f) {
    unsigned int u = __float_as_uint(f);
    unsigned int r = (u + 0x7FFFu + ((u >> 16) & 1u)) >> 16;
    return (unsigned short)r;
}
__device__ __forceinline__ float bf2f(unsigned short b) {
    return __uint_as_float(((unsigned int)b) << 16);
}
__device__ __forceinline__ float2 bf2f2(unsigned int p) {
    float2 r;
    r.x = __uint_as_float(p << 16);
    r.y = __uint_as_float(p & 0xFFFF0000u);
    return r;
}
__device__ __forceinline__ void unpack_edge(unsigned long long p, int& s, float& eav) {
    s = (int)(unsigned int)(p & 0xFFFFFFFFull);
    eav = __uint_as_float((unsigned int)(p >> 32));
}
// select one of 4 by runtime index without scratch-spilling arrays (rule #20)
__device__ __forceinline__ float pick4(float a, float b, float c, float d, int h) {
    return (h & 2) ? ((h & 1) ? d : c) : ((h & 1) ? b : a);
}

// 256-thread exclusive scan (ONE internal barrier; all 256 must call)
__device__ __forceinline__ int block_excl_scan_256(int v, int tid, int* wsum) {
    int lane = tid & 63, wv = tid >> 6;
    int x = v;
    #pragma unroll
    for (int off = 1; off < 64; off <<= 1) {
        int y = __shfl_up(x, off);
        if (lane >= off) x += y;
    }
    if (lane == 63) wsum[wv] = x;
    __syncthreads();
    int wpre = 0;
    #pragma unroll
    for (int w = 0; w < 4; w++)
        if (w < wv) wpre += wsum[w];
    return wpre + x - v;
}

// ---------------- K0: W1/W2 frag prepack + attn consts + zero-init ----------------
__global__ __launch_bounds__(256) void k0_prep(const float* __restrict__ W1,
                                               const float* __restrict__ W2,
                                               const float* __restrict__ We1,
                                               const float* __restrict__ ae1,
                                               const float* __restrict__ We2,
                                               const float* __restrict__ ae2,
                                               unsigned short* __restrict__ W1hi,
                                               unsigned short* __restrict__ W1lo,
                                               unsigned short* __restrict__ W2hi,
                                               unsigned short* __restrict__ W2lo,
                                               float* __restrict__ consts,
                                               int* __restrict__ bucketHist,
                                               int* __restrict__ bucketCursor,
                                               int* __restrict__ indptr) {
    int blk = blockIdx.x;
    int tid = threadIdx.x;
    if (blk < 16) {
        // W1 [256,128] -> frag order ((nt*8+kt)*64+lane)*8+j, split hi/lo
        int t = blk * 256 + tid;
        int lane = t & 63;
        int kt = (t >> 6) & 7;
        int nt = t >> 9;
        int kbase = kt * 32 + (lane >> 4) * 8;
        int col = nt * 16 + (lane & 15);
        size_t obase = (size_t)t * 8;
        #pragma unroll
        for (int j = 0; j < 8; j++) {
            float w = W1[(size_t)(kbase + j) * HC + col];
            unsigned short h = f2bf(w);
            W1hi[obase + j] = h;
            W1lo[obase + j] = f2bf(w - bf2f(h));
        }
    } else if (blk < 18) {
        // W2 [128,32] -> frag order ((nt*4+kt)*64+lane)*8+j, split hi/lo
        int t = (blk - 16) * 256 + tid;  // 0..511
        int lane = t & 63;
        int kt = (t >> 6) & 3;
        int nt = t >> 8;
        int kbase = kt * 32 + (lane >> 4) * 8;
        int col = nt * 16 + (lane & 15);
        size_t obase = (size_t)t * 8;
        #pragma unroll
        for (int j = 0; j < 8; j++) {
            float w = W2[(size_t)(kbase + j) * CD + col];
            unsigned short h = f2bf(w);
            W2hi[obase + j] = h;
            W2lo[obase + j] = f2bf(w - bf2f(h));
        }
    } else {
        if (tid < NBKT) { bucketHist[tid] = 0; bucketCursor[tid] = 0; }
        if (tid == 200) consts[0] = 0.f;     // easum accumulator
        if (tid == 201) indptr[NN] = EE;     // constant sentinel
        if (tid < 4) {
            float s = 0.f;
            for (int c = 0; c < 32; c++) s += We1[tid * 32 + c] * ae1[tid * 32 + c];
            consts[2 + tid] = s;
        } else if (tid == 4) {
            float s = 0.f;
            for (int c = 0; c < 32; c++) s += We2[c] * ae2[c];
            consts[6] = s;
        }
    }
}

// ---------------- K_A: hist (LDS) || gemm1 (MFMA split-bf16), fused ----------------
// gemm1 hoists ALL 16 x-row loads before the MFMA loop: the kernel is latency-bound
// at ~4 waves/SIMD (r8 counters), so 16-deep ILP replaces the missing TLP.
__global__ __launch_bounds__(256) void kA_hist_gemm1(const int* __restrict__ ei,
                                                     const float* __restrict__ ea,
                                                     const float* __restrict__ x,
                                                     const unsigned short* __restrict__ Whi,
                                                     const unsigned short* __restrict__ Wlo,
                                                     int* __restrict__ bucketHist,
                                                     float* __restrict__ easum,
                                                     unsigned short* __restrict__ xs1b) {
    __shared__ int h[256];
    int tid = threadIdx.x;
    if (blockIdx.x < HIST_B) {
        h[tid] = 0;
        __syncthreads();
        float s = 0.f;
        for (int i = blockIdx.x * 256 + tid; i < EE; i += HIST_B * 256) {
            atomicAdd(&h[ei[EE + i] >> 8], 1);
            s += ea[i];
        }
        __syncthreads();
        if (tid < NBKT && h[tid] > 0) atomicAdd(&bucketHist[tid], h[tid]);
        #pragma unroll
        for (int off = 32; off > 0; off >>= 1) s += __shfl_xor(s, off);
        if ((tid & 63) == 0) atomicAdd(easum, s);
    } else {
        int lane = tid & 63, wv = tid >> 6;
        int row0 = (blockIdx.x - HIST_B) * 64 + wv * 16;
        if (row0 >= NN) return;
        int m = lane & 15;
        int q = lane >> 4;
        const float* xrow = x + (size_t)(row0 + m) * IN_DIM + q * 8;
        // hoisted x loads: 16 float4 in flight (statically indexed -> registers)
        float4 xv[16];
        #pragma unroll
        for (int kt = 0; kt < 8; kt++) {
            xv[kt * 2]     = *(const float4*)(xrow + kt * 32);
            xv[kt * 2 + 1] = *(const float4*)(xrow + kt * 32 + 4);
        }
        f32x4 acc[8];
        #pragma unroll
        for (int nt = 0; nt < 8; nt++) acc[nt] = {0.f, 0.f, 0.f, 0.f};
        #pragma unroll
        for (int kt = 0; kt < 8; kt++) {
            float4 v0 = xv[kt * 2];
            float4 v1 = xv[kt * 2 + 1];
            float vv[8] = {v0.x, v0.y, v0.z, v0.w, v1.x, v1.y, v1.z, v1.w};
            short8 ahi, alo;
            #pragma unroll
            for (int j = 0; j < 8; j++) {
                unsigned short hh = f2bf(vv[j]);
                ahi[j] = (short)hh;
                alo[j] = (short)f2bf(vv[j] - bf2f(hh));
            }
            #pragma unroll
            for (int nt = 0; nt < 8; nt++) {
                size_t fb = ((size_t)(nt * 8 + kt) * 64 + lane) * 8;
                short8 bhi = *(const short8*)(Whi + fb);
                short8 blo = *(const short8*)(Wlo + fb);
                acc[nt] = __builtin_amdgcn_mfma_f32_16x16x32_bf16(ahi, bhi, acc[nt], 0, 0, 0);
                acc[nt] = __builtin_amdgcn_mfma_f32_16x16x32_bf16(ahi, blo, acc[nt], 0, 0, 0);
                acc[nt] = __builtin_amdgcn_mfma_f32_16x16x32_bf16(alo, bhi, acc[nt], 0, 0, 0);
            }
        }
        #pragma unroll
        for (int nt = 0; nt < 8; nt++) {
            #pragma unroll
            for (int rg = 0; rg < 4; rg++) {
                int row = row0 + q * 4 + rg;
                xs1b[(size_t)row * HC + nt * 16 + m] = f2bf(acc[nt][rg]);
            }
        }
    }
}

// ---------------- K_B: stage1 (bucket bin, packed 8B records) || al1, fused --------
// record: w0 = src | (dst&255)<<24  (src<2^24, bucket implicit in position), w1 = ea
// Each stage1 block computes the global bucket prefix from bucketHist itself
// (cursor starts at 0) — replaces the former single-block bucket_scan launch.
__global__ __launch_bounds__(256) void kB_stage1_al1(const int* __restrict__ ei,
                                                     const float* __restrict__ ea,
                                                     const int* __restrict__ bucketHist,
                                                     int* __restrict__ bucketCursor,
                                                     uint2* __restrict__ Apack,
                                                     const unsigned short* __restrict__ xs1b,
                                                     const float* __restrict__ as1,
                                                     const float* __restrict__ ad1,
                                                     float* __restrict__ als,
                                                     float* __restrict__ ald) {
    __shared__ int cnt[256];
    __shared__ int basel[256];
    __shared__ int gbase[256];
    __shared__ int wsum[4];
    __shared__ int wsum2[4];
    __shared__ int sdst[2048];
    __shared__ int ssrc[2048];
    __shared__ float sea[2048];
    int tid = threadIdx.x;
    if (blockIdx.x < S1_B) {
        cnt[tid] = 0;
        int hv = (tid < NBKT) ? bucketHist[tid] : 0;
        // internal barrier also publishes the cnt zeros
        int hexcl = block_excl_scan_256(hv, tid, wsum2);
        int base = blockIdx.x * 2048;
        int d[8], s[8], r[8], bk[8];
        float e[8];
        #pragma unroll
        for (int k = 0; k < 8; k++) {
            int i = base + k * 256 + tid;
            if (i < EE) {
                d[k] = ei[EE + i];
                s[k] = ei[i];
                e[k] = ea[i];
                bk[k] = d[k] >> 8;
                r[k] = atomicAdd(&cnt[bk[k]], 1);   // LDS returning atomic: cheap
            } else d[k] = -1;
        }
        __syncthreads();
        int v = cnt[tid];
        int excl = block_excl_scan_256(v, tid, wsum);
        basel[tid] = excl;
        if (tid < NBKT) gbase[tid] = hexcl + atomicAdd(&bucketCursor[tid], v);
        __syncthreads();
        #pragma unroll
        for (int k = 0; k < 8; k++) {
            if (d[k] >= 0) {
                int slot = basel[bk[k]] + r[k];
                sdst[slot] = d[k];
                ssrc[slot] = s[k];
                sea[slot] = e[k];
            }
        }
        __syncthreads();
        int total = basel[255] + cnt[255];
        for (int slot = tid; slot < total; slot += 256) {
            int dd = sdst[slot];
            int b = dd >> 8;
            int pos = gbase[b] + (slot - basel[b]);
            Apack[pos] = make_uint2((unsigned int)ssrc[slot] | ((unsigned int)(dd & 255) << 24),
                                    __float_as_uint(sea[slot]));
        }
    } else {
        // ---- al1 path: one thread per (node,head) — hidden next to stage1 blocks ----
        int t = (blockIdx.x - S1_B) * 256 + tid;
        if (t < NN * 4) {
            int hh = t & 3;
            const unsigned int* xp = (const unsigned int*)(xs1b + (size_t)t * 32);
            const float* ap = as1 + hh * 32;
            const float* dp = ad1 + hh * 32;
            float s = 0.f, d = 0.f;
            #pragma unroll
            for (int q = 0; q < 16; q++) {
                float2 v = bf2f2(xp[q]);
                s += v.x * ap[q * 2] + v.y * ap[q * 2 + 1];
                d += v.x * dp[q * 2] + v.y * dp[q * 2 + 1];
            }
            als[t] = s;
            ald[t] = d;
        }
    }
}

// ---------------- stage2 (1024 threads): per-bucket counting sort -> indptr + edgedat ----
// Computes its own bucket base from bucketHist (replaces bucket_scan's bucketBase).
__global__ __launch_bounds__(1024) void stage2_kernel(const int* __restrict__ bucketHist,
                                                      const uint2* __restrict__ Apack,
                                                      int* __restrict__ indptr,
                                                      unsigned long long* __restrict__ edgedat,
                                                      float* __restrict__ consts) {
    __shared__ int cnt[256];
    __shared__ int dbase[256];
    __shared__ int s_start;
    int tid = threadIdx.x;
    int b = blockIdx.x;
    if (b == 0 && tid == 0) consts[1] = consts[0] / (float)EE;  // ea_mean finalize
    if (tid < 64) {
        int p = 0;
        for (int i = tid; i < b; i += 64) p += bucketHist[i];
        #pragma unroll
        for (int off = 32; off > 0; off >>= 1) p += __shfl_xor(p, off);
        if (tid == 0) s_start = p;
    }
    if (tid < 256) cnt[tid] = 0;
    __syncthreads();
    int start = s_start;
    int end = start + bucketHist[b];
    for (int i = start + tid; i < end; i += 1024) atomicAdd(&cnt[Apack[i].x >> 24], 1);
    __syncthreads();
    // exclusive scan of 256 bins by wave 0 (4 bins/lane)
    if (tid < 64) {
        int b4 = tid * 4;
        int c0 = cnt[b4], c1 = cnt[b4 + 1], c2 = cnt[b4 + 2], c3 = cnt[b4 + 3];
        int t = c0 + c1 + c2 + c3;
        int x = t;
        #pragma unroll
        for (int off = 1; off < 64; off <<= 1) {
            int y = __shfl_up(x, off);
            if (tid >= off) x += y;
        }
        int e0 = x - t;
        dbase[b4] = e0;
        dbase[b4 + 1] = e0 + c0;
        dbase[b4 + 2] = e0 + c0 + c1;
        dbase[b4 + 3] = e0 + c0 + c1 + c2;
    }
    __syncthreads();
    if (tid < 256) {
        int n = b * 256 + tid;
        if (n < NN) indptr[n] = start + dbase[tid];
        cnt[tid] = 0;          // reuse as per-dst cursor
    }
    __syncthreads();
    for (int i = start + tid; i < end; i += 1024) {
        uint2 p = Apack[i];
        int dl = p.x >> 24;
        int r = atomicAdd(&cnt[dl], 1);
        int pos = start + dbase[dl] + r;
        edgedat[pos] = (unsigned long long)(p.x & 0xFFFFFFu) |
                       ((unsigned long long)p.y << 32);
    }
}

// accumulate one gathered uint2 (4 bf16 cols) with raw weight ww
#define ACC4(vv, ww) { float2 p0_ = bf2f2((vv).x); float2 p1_ = bf2f2((vv).y); \
    acc0 += p0_.x * (ww); acc1 += p0_.y * (ww); acc2 += p1_.x * (ww); acc3 += p1_.y * (ww); }

// ---------------- conv1 aggregation + FUSED gemm2 (h1 never leaves the block) ------
#define H1P 136   // h1 LDS row pitch (ushorts): 272B = 16B-aligned, spreads banks
__global__ __launch_bounds__(256, 8) void gat1_gemm2(
    const unsigned short* __restrict__ xs1b, const float* __restrict__ als,
    const float* __restrict__ ald, const unsigned long long* __restrict__ edgedat,
    const int* __restrict__ indptr, const float* __restrict__ consts,
    const float* __restrict__ b1, const float* __restrict__ g1,
    const float* __restrict__ be1,
    const unsigned short* __restrict__ W2hi, const unsigned short* __restrict__ W2lo,
    const float* __restrict__ as2, const float* __restrict__ ad2,
    unsigned short* __restrict__ xs2b, float* __restrict__ als2,
    float* __restrict__ ald2) {
    __shared__ __align__(16) float exbuf[8][CAP1][4];
    __shared__ int srcbuf[8][CAP1];
    __shared__ __align__(16) unsigned short h1hi_s[8][H1P];
    __shared__ __align__(16) unsigned short h1lo_s[8][H1P];
    int tid = threadIdx.x;
    int l = tid & 31;            // lane within half-wave
    int nb = tid >> 5;           // node slot 0..7
    int n = blockIdx.x * 8 + nb;
    int start = indptr[n];
    int deg = indptr[n + 1] - start;
    float ea_mean = consts[1];
    float ce0 = consts[2], ce1 = consts[3], ce2 = consts[4], ce3 = consts[5];
    float4 a4d = *(const float4*)(ald + (size_t)n * 4);
    float4 a4s = *(const float4*)(als + (size_t)n * 4);
    float ex00 = __expf(lrelu(a4s.x + a4d.x + ea_mean * ce0));
    float ex01 = __expf(lrelu(a4s.y + a4d.y + ea_mean * ce1));
    float ex02 = __expf(lrelu(a4s.z + a4d.z + ea_mean * ce2));
    float ex03 = __expf(lrelu(a4s.w + a4d.w + ea_mean * ce3));
    float sm0 = 0.f, sm1 = 0.f, sm2 = 0.f, sm3 = 0.f;
    const unsigned long long* edp = edgedat + start;
    // phase 1: raw exp weights -> LDS, per-head partial sums
    for (int i = l; i < deg; i += 32) {
        int s; float eav;
        unpack_edge(edp[i], s, eav);
        float4 v4 = *(const float4*)(als + (size_t)s * 4);
        float4 ex4;
        ex4.x = __expf(lrelu(v4.x + a4d.x + eav * ce0)); sm0 += ex4.x;
        ex4.y = __expf(lrelu(v4.y + a4d.y + eav * ce1)); sm1 += ex4.y;
        ex4.z = __expf(lrelu(v4.z + a4d.z + eav * ce2)); sm2 += ex4.z;
        ex4.w = __expf(lrelu(v4.w + a4d.w + eav * ce3)); sm3 += ex4.w;
        if (i < CAP1) {
            srcbuf[nb][i] = s * (HC * 2);                   // byte offset of src row
            *(float4*)(&exbuf[nb][i][0]) = ex4;
        }
    }
    #pragma unroll
    for (int off = 16; off > 0; off >>= 1) {
        sm0 += __shfl_xor(sm0, off);
        sm1 += __shfl_xor(sm1, off);
        sm2 += __shfl_xor(sm2, off);
        sm3 += __shfl_xor(sm3, off);
    }
    int h2 = l >> 3;                                         // this lane's head
    float ex0sel = pick4(ex00, ex01, ex02, ex03, h2);
    float inv = 1.0f / (pick4(sm0, sm1, sm2, sm3, h2) + ex0sel + 1e-16f);
    int mcap = deg < CAP1 ? deg : CAP1;
    const char* xb = (const char*)xs1b + (size_t)l * 8;      // lane's 4 cols (8B)
    float acc0, acc1, acc2, acc3;
    {   // self loop (raw weight)
        uint2 v = *(const uint2*)(xb + (size_t)n * (HC * 2));
        float2 p0 = bf2f2(v.x), p1 = bf2f2(v.y);
        acc0 = p0.x * ex0sel; acc1 = p0.y * ex0sel;
        acc2 = p1.x * ex0sel; acc3 = p1.y * ex0sel;
    }
    // phase 2: weighted gather, 8 loads in flight
    int i = 0;
    for (; i + 8 <= mcap; i += 8) {
        int o0 = srcbuf[nb][i + 0], o1 = srcbuf[nb][i + 1];
        int o2 = srcbuf[nb][i + 2], o3 = srcbuf[nb][i + 3];
        int o4 = srcbuf[nb][i + 4], o5 = srcbuf[nb][i + 5];
        int o6 = srcbuf[nb][i + 6], o7 = srcbuf[nb][i + 7];
        float w0 = exbuf[nb][i + 0][h2], w1 = exbuf[nb][i + 1][h2];
        float w2 = exbuf[nb][i + 2][h2], w3 = exbuf[nb][i + 3][h2];
        float w4 = exbuf[nb][i + 4][h2], w5 = exbuf[nb][i + 5][h2];
        float w6 = exbuf[nb][i + 6][h2], w7 = exbuf[nb][i + 7][h2];
        uint2 v0 = *(const uint2*)(xb + o0);
        uint2 v1 = *(const uint2*)(xb + o1);
        uint2 v2 = *(const uint2*)(xb + o2);
        uint2 v3 = *(const uint2*)(xb + o3);
        uint2 v4 = *(const uint2*)(xb + o4);
        uint2 v5 = *(const uint2*)(xb + o5);
        uint2 v6 = *(const uint2*)(xb + o6);
        uint2 v7 = *(const uint2*)(xb + o7);
        ACC4(v0, w0); ACC4(v1, w1); ACC4(v2, w2); ACC4(v3, w3);
        ACC4(v4, w4); ACC4(v5, w5); ACC4(v6, w6); ACC4(v7, w7);
    }
    for (; i < mcap; i++) {
        int o = srcbuf[nb][i];
        float w = exbuf[nb][i][h2];
        uint2 v = *(const uint2*)(xb + o);
        ACC4(v, w);
    }
    if (deg > CAP1) {   // spill fallback (deg > CAP1): recompute raw weights (cold)
        float aldsel = pick4(a4d.x, a4d.y, a4d.z, a4d.w, h2);
        float cesel = pick4(ce0, ce1, ce2, ce3, h2);
        for (int j = CAP1; j < deg; j++) {
            int s; float eav;
            unpack_edge(edp[j], s, eav);
            float w = __expf(lrelu(als[(size_t)s * 4 + h2] + aldsel + eav * cesel));
            uint2 v = *(const uint2*)(xb + (size_t)s * (HC * 2));
            ACC4(v, w);
        }
    }
    acc0 *= inv; acc1 *= inv; acc2 *= inv; acc3 *= inv;
    int c = l * 4;
    float4 bb = *(const float4*)(b1 + c);
    float4 gg = *(const float4*)(g1 + c);
    float4 eb = *(const float4*)(be1 + c);
    float o0 = elu((acc0 + bb.x) * (gg.x * BN_RS) + eb.x);
    float o1 = elu((acc1 + bb.y) * (gg.y * BN_RS) + eb.y);
    float o2 = elu((acc2 + bb.z) * (gg.z * BN_RS) + eb.z);
    float o3 = elu((acc3 + bb.w) * (gg.w * BN_RS) + eb.w);
    // split hi/lo bf16 into LDS for the fused gemm2
    unsigned short h0 = f2bf(o0), h1v = f2bf(o1), h2v = f2bf(o2), h3v = f2bf(o3);
    unsigned short l0 = f2bf(o0 - bf2f(h0)), l1 = f2bf(o1 - bf2f(h1v));
    unsigned short l2 = f2bf(o2 - bf2f(h2v)), l3 = f2bf(o3 - bf2f(h3v));
    uint2 hiw, low;
    hiw.x = (unsigned int)h0 | ((unsigned int)h1v << 16);
    hiw.y = (unsigned int)h2v | ((unsigned int)h3v << 16);
    low.x = (unsigned int)l0 | ((unsigned int)l1 << 16);
    low.y = (unsigned int)l2 | ((unsigned int)l3 << 16);
    *(uint2*)(&h1hi_s[nb][c]) = hiw;
    *(uint2*)(&h1lo_s[nb][c]) = low;
    __syncthreads();             // h1 tile complete
    if (tid >= 64) return;       // waves 1-3 done

    // ---- wave 0: gemm2 (16x16x32 MFMA) for rows n0..n0+7 ----
    int lane = tid;              // 0..63
    int m = lane & 15, q = lane >> 4;
    int r8 = m & 7;              // rows 8..15 duplicate 0..7 (outputs discarded)
    f32x4 g2acc0 = {0.f, 0.f, 0.f, 0.f};
    f32x4 g2acc1 = {0.f, 0.f, 0.f, 0.f};
    #pragma unroll
    for (int kt = 0; kt < 4; kt++) {
        short8 ahi = *(const short8*)(&h1hi_s[r8][q * 8 + kt * 32]);
        short8 alo = *(const short8*)(&h1lo_s[r8][q * 8 + kt * 32]);
        size_t fb0 = ((size_t)kt * 64 + lane) * 8;
        size_t fb1 = ((size_t)(4 + kt) * 64 + lane) * 8;
        short8 bhi0 = *(const short8*)(W2hi + fb0);
        short8 blo0 = *(const short8*)(W2lo + fb0);
        short8 bhi1 = *(const short8*)(W2hi + fb1);
        short8 blo1 = *(const short8*)(W2lo + fb1);
        g2acc0 = __builtin_amdgcn_mfma_f32_16x16x32_bf16(ahi, bhi0, g2acc0, 0, 0, 0);
        g2acc0 = __builtin_amdgcn_mfma_f32_16x16x32_bf16(ahi, blo0, g2acc0, 0, 0, 0);
        g2acc0 = __builtin_amdgcn_mfma_f32_16x16x32_bf16(alo, bhi0, g2acc0, 0, 0, 0);
        g2acc1 = __builtin_amdgcn_mfma_f32_16x16x32_bf16(ahi, bhi1, g2acc1, 0, 0, 0);
        g2acc1 = __builtin_amdgcn_mfma_f32_16x16x32_bf16(ahi, blo1, g2acc1, 0, 0, 0);
        g2acc1 = __builtin_amdgcn_mfma_f32_16x16x32_bf16(alo, bhi1, g2acc1, 0, 0, 0);
    }
    int n0 = blockIdx.x * 8;
    float a0 = as2[m], a1 = as2[m + 16];
    float d0 = ad2[m], d1 = ad2[m + 16];
    #pragma unroll
    for (int rg = 0; rg < 4; rg++) {
        int rloc = q * 4 + rg;       // 0..15; valid output rows are 0..7
        float s = g2acc0[rg] * a0 + g2acc1[rg] * a1;
        float d = g2acc0[rg] * d0 + g2acc1[rg] * d1;
        #pragma unroll
        for (int off = 1; off < 16; off <<= 1) {
            s += __shfl_xor(s, off);
            d += __shfl_xor(d, off);
        }
        if (rloc < 8) {
            int row = n0 + rloc;
            xs2b[(size_t)row * CD + m]      = f2bf(g2acc0[rg]);
            xs2b[(size_t)row * CD + 16 + m] = f2bf(g2acc1[rg]);
            if (m == 0) { als2[row] = s; ald2[row] = d; }
        }
    }
}

// ---------------- conv2 aggregation + fused MLP heads (raw-acc + post-scale) --------
// Half-wave per node (8 nodes/block): deg~32 so 32 lanes/node doubles phase-1 lane
// utilization vs the old wave-per-node layout. 4-oct phase 2, MLP on the same 32 lanes.
__global__ __launch_bounds__(256) void gat2_agg(
    const unsigned short* __restrict__ xs2b, const float* __restrict__ als,
    const float* __restrict__ ald, const unsigned long long* __restrict__ edgedat,
    const int* __restrict__ indptr, const float* __restrict__ consts,
    const float* __restrict__ b2, const float* __restrict__ g2, const float* __restrict__ be2,
    const float* __restrict__ Wc1, const float* __restrict__ bc1,
    const float* __restrict__ Wc2, const float* __restrict__ bc2,
    const float* __restrict__ Wr1, const float* __restrict__ br1,
    const float* __restrict__ Wr2, const float* __restrict__ br2,
    float* __restrict__ hout, float* __restrict__ cls, float* __restrict__ reg) {
    __shared__ float exbuf[8][CAP2];
    __shared__ int srcbuf[8][CAP2];
    __shared__ __align__(16) float hbuf[8][32];
    int tid = threadIdx.x;
    int l = tid & 31;            // lane within half-wave
    int nb = tid >> 5;           // node slot 0..7
    int n = blockIdx.x * 8 + nb;
    int start = indptr[n];
    int deg = indptr[n + 1] - start;
    float ea_mean = consts[1];
    float ce = consts[6];
    float aldn = ald[n];
    float ex0 = __expf(lrelu(als[n] + aldn + ea_mean * ce));
    float sm = 0.f;
    const unsigned long long* edp = edgedat + start;
    for (int i = l; i < deg; i += 32) {
        int s; float eav;
        unpack_edge(edp[i], s, eav);
        float exv = __expf(lrelu(als[s] + aldn + eav * ce));
        if (i < CAP2) { srcbuf[nb][i] = s * (CD * 2); exbuf[nb][i] = exv; }
        sm += exv;
    }
    #pragma unroll
    for (int off = 16; off > 0; off >>= 1) sm += __shfl_xor(sm, off);
    float invd = 1.0f / (sm + ex0 + 1e-16f);
    int mcap = deg < CAP2 ? deg : CAP2;
    int oct = l >> 3, lo = l & 7;
    const char* xb = (const char*)xs2b + (size_t)lo * 8;     // lane's 4 cols (8B)
    float acc0 = 0.f, acc1 = 0.f, acc2 = 0.f, acc3 = 0.f;
    if (oct == 0) {   // self loop (raw weight), counted once after oct-reduce
        uint2 v = *(const uint2*)(xb + (size_t)n * (CD * 2));
        float2 p0 = bf2f2(v.x), p1 = bf2f2(v.y);
        acc0 = p0.x * ex0; acc1 = p0.y * ex0; acc2 = p1.x * ex0; acc3 = p1.y * ex0;
    }
    for (int i = oct; i < mcap; i += 4) {
        float w = exbuf[nb][i];
        int o = srcbuf[nb][i];
        uint2 v = *(const uint2*)(xb + o);
        ACC4(v, w);
    }
    for (int i = CAP2 + oct; i < deg; i += 4) {  // spill fallback (raw weights)
        int s; float eav;
        unpack_edge(edp[i], s, eav);
        float w = __expf(lrelu(als[s] + aldn + eav * ce));
        uint2 v = *(const uint2*)(xb + (size_t)s * (CD * 2));
        ACC4(v, w);
    }
    // reduce across the 4 octs (stays within the 32-lane half)
    #pragma unroll
    for (int off = 8; off < 32; off <<= 1) {
        acc0 += __shfl_xor(acc0, off);
        acc1 += __shfl_xor(acc1, off);
        acc2 += __shfl_xor(acc2, off);
        acc3 += __shfl_xor(acc3, off);
    }
    if (l < 8) {
        int c = lo * 4;
        float4 bb = *(const float4*)(b2 + c);
        float4 gg = *(const float4*)(g2 + c);
        float4 eb = *(const float4*)(be2 + c);
        float o0 = elu((acc0 * invd + bb.x) * (gg.x * BN_RS) + eb.x);
        float o1 = elu((acc1 * invd + bb.y) * (gg.y * BN_RS) + eb.y);
        float o2 = elu((acc2 * invd + bb.z) * (gg.z * BN_RS) + eb.z);
        float o3 = elu((acc3 * invd + bb.w) * (gg.w * BN_RS) + eb.w);
        *(float4*)(&hbuf[nb][c]) = make_float4(o0, o1, o2, o3);
        *(float4*)(hout + (size_t)n * CD + c) = make_float4(o0, o1, o2, o3);
    }
    // intra-wave LDS RAW: no block barrier needed (hbuf slot owned by this half-wave)
    float r0 = 0.f, r1 = 0.f;
    {
        int j = l & 15;
        bool iscls = l < 16;
        float s = iscls ? bc1[j] : br1[j];
        #pragma unroll
        for (int cc = 0; cc < 32; cc++) {
            float w = iscls ? Wc1[cc * 16 + j] : Wr1[cc * 16 + j];
            s += hbuf[nb][cc] * w;
        }
        s = fmaxf(s, 0.f);
        if (iscls) { r0 = s * Wc2[j * 2]; r1 = s * Wc2[j * 2 + 1]; }
        else       { r0 = s * Wr2[j]; }
    }
    #pragma unroll
    for (int off = 1; off < 16; off <<= 1) {
        r0 += __shfl_xor(r0, off);
        r1 += __shfl_xor(r1, off);
    }
    if (l == 0)  *(float2*)(cls + (size_t)n * 2) = make_float2(r0 + bc2[0], r1 + bc2[1]);
    if (l == 16) reg[n] = r0 + br2[0];
}

// ---------------- launch ----------------
extern "C" void kernel_launch(void* const* d_in, const int* in_sizes, int n_in,
                              void* d_out, int out_size, void* d_ws, size_t ws_size,
                              hipStream_t stream) {
    const float* x   = (const float*)d_in[0];
    const int*   ei  = (const int*)d_in[1];
    const float* ea  = (const float*)d_in[2];
    const float* W1  = (const float*)d_in[3];
    const float* as1 = (const float*)d_in[4];
    const float* ad1 = (const float*)d_in[5];
    const float* We1 = (const float*)d_in[6];
    const float* ae1 = (const float*)d_in[7];
    const float* b1  = (const float*)d_in[8];
    const float* g1  = (const float*)d_in[9];
    const float* be1 = (const float*)d_in[10];
    const float* W2  = (const float*)d_in[11];
    const float* as2 = (const float*)d_in[12];
    const float* ad2 = (const float*)d_in[13];
    const float* We2 = (const float*)d_in[14];
    const float* ae2 = (const float*)d_in[15];
    const float* b2  = (const float*)d_in[16];
    const float* g2  = (const float*)d_in[17];
    const float* be2 = (const float*)d_in[18];
    const float* Wc1 = (const float*)d_in[19];
    const float* bc1 = (const float*)d_in[20];
    const float* Wc2 = (const float*)d_in[21];
    const float* bc2 = (const float*)d_in[22];
    const float* Wr1 = (const float*)d_in[23];
    const float* br1 = (const float*)d_in[24];
    const float* Wr2 = (const float*)d_in[25];
    const float* br2 = (const float*)d_in[26];

    char* ws = (char*)d_ws;
    unsigned short* xs1b = (unsigned short*)(ws + 0);          // N*128 bf16 = 12.8 MB
    uint2* Apack         = (uint2*)(ws + 12800000);            // E*8 = 12.8 MB (dead after stage2)
    unsigned short* xs2b = (unsigned short*)(ws + 38400000);   // N*32 bf16 = 3.2 MB
    float* als1          = (float*)(ws + 41600000);            // N*4
    float* ald1          = (float*)(ws + 42400000);            // N*4
    float* als2          = (float*)(ws + 43200000);            // N
    float* ald2          = (float*)(ws + 43400000);            // N
    float* consts        = (float*)(ws + 43600000);            // 8 floats
    int*   bucketHist    = (int*)(ws + 43600128);              // 196
    int*   bucketCursor  = (int*)(ws + 43601920);              // 196
    int*   indptr        = (int*)(ws + 43602816);              // N+1
    unsigned long long* edgedat = (unsigned long long*)(ws + 43802824);  // E*8 -> ends 56602824
    unsigned short* W1hi = (unsigned short*)(ws + 56602832);   // 64 KB
    unsigned short* W1lo = (unsigned short*)(ws + 56668368);   // 64 KB
    unsigned short* W2hi = (unsigned short*)(ws + 56733904);   // 8 KB
    unsigned short* W2lo = (unsigned short*)(ws + 56742096);   // 8 KB (ends ~56.75 MB)

    float* out_cls = (float*)d_out;            // [N,2]
    float* out_reg = out_cls + 2 * NN;         // [N]
    float* out_h   = out_cls + 3 * NN;         // [N,32]

    // K0: weight prepacks + attn consts + zero-init (hist, cursors) + indptr sentinel
    k0_prep<<<19, 256, 0, stream>>>(W1, W2, We1, ae1, We2, ae2,
                                    W1hi, W1lo, W2hi, W2lo, consts,
                                    bucketHist, bucketCursor, indptr);
    // K_A: hist || gemm1 (hoisted x loads) — heterogeneous co-scheduled launch
    kA_hist_gemm1<<<HIST_B + G1_B, 256, 0, stream>>>(ei, ea, x, W1hi, W1lo,
                                                     bucketHist, consts, xs1b);
    // K_B: stage1 (per-block bucket prefix, packed 8B records) || al1 (hidden)
    kB_stage1_al1<<<S1_B + 782, 256, 0, stream>>>(ei, ea, bucketHist, bucketCursor,
                                                  Apack, xs1b, as1, ad1, als1, ald1);
    // stage2: per-bucket counting sort -> indptr + edgedat (+ ea_mean finalize)
    stage2_kernel<<<NBKT, 1024, 0, stream>>>(bucketHist, Apack, indptr, edgedat, consts);

    // gat1 + gemm2 fused: h1 stays in LDS; writes xs2b/als2/ald2 directly
    gat1_gemm2<<<NN / 8, 256, 0, stream>>>(xs1b, als1, ald1, edgedat, indptr, consts,
                                           b1, g1, be1, W2hi, W2lo, as2, ad2,
                                           xs2b, als2, ald2);
    // gat2: half-wave per node, 8 nodes/block
    gat2_agg<<<NN / 8, 256, 0, stream>>>(xs2b, als2, ald2, edgedat, indptr, consts,
                                         b2, g2, be2, Wc1, bc1, Wc2, bc2,
                                         Wr1, br1, Wr2, br2, out_h, out_cls, out_reg);
}